// Round 6
// baseline (691.429 us; speedup 1.0000x reference)
//
#include <hip/hip_runtime.h>
#include <hip/hip_bf16.h>
#include <stdint.h>

#define NN 50000
#define NE 1600000
#define INC 116
#define K1P 128     // padded layer-1 input channels (8 panels x 16)
#define HID 256
#define OUTC 2

typedef float f32x4 __attribute__((ext_vector_type(4)));
typedef short s16x8 __attribute__((ext_vector_type(8)));

// bf16 helpers (round-to-nearest-even), bit-level
__device__ __forceinline__ ushort f2bf(float v) {
    uint32_t u = __float_as_uint(v);
    return (ushort)((u + 0x7FFFu + ((u >> 16) & 1u)) >> 16);
}
__device__ __forceinline__ float bf2f(ushort b) {
    return __uint_as_float(((uint32_t)b) << 16);
}
__device__ __forceinline__ float bflo(uint32_t u) { return __uint_as_float(u << 16); }
__device__ __forceinline__ float bfhi(uint32_t u) { return __uint_as_float(u & 0xFFFF0000u); }

// ---------------- edge-index format hedge (int32 vs int64) ----------------
__global__ void detect_fmt(const int* __restrict__ ebuf, int* __restrict__ flag) {
    int v = ebuf[2 * threadIdx.x + 1];
    unsigned long long b = __ballot(v != 0);
    if (threadIdx.x == 0) flag[0] = (b == 0ULL) ? 1 : 0;
}

__device__ __forceinline__ int edge_at(const int* __restrict__ ebuf, int is64, int idx) {
    return is64 ? ebuf[2 * idx] : ebuf[idx];
}

// ---------------- degree histogram (XCD-local dst ranges) ----------------
__global__ void __launch_bounds__(256)
deg_hist2(const int* __restrict__ ebuf, const int* __restrict__ flag,
          int* __restrict__ cnt) {
    int rng = blockIdx.x & 7;
    int lo = rng * (NN / 8), hi = lo + (NN / 8);
    int is64 = flag[0];
    int stride = (gridDim.x >> 3) * 256;
    for (int e = (blockIdx.x >> 3) * 256 + threadIdx.x; e < NE; e += stride) {
        int d = edge_at(ebuf, is64, NE + e);
        if (d >= lo && d < hi) atomicAdd(&cnt[d], 1);
    }
}

__global__ void dinv_kernel(const int* __restrict__ cnt, float* __restrict__ dinv) {
    int n = blockIdx.x * blockDim.x + threadIdx.x;
    if (n < NN) dinv[n] = rsqrtf((float)cnt[n] + 1.0f);
}

// ---------------- prefix scan ----------------
__global__ void scan1(const int* __restrict__ cnt, int* __restrict__ rowptr,
                      int* __restrict__ bsum) {
    __shared__ int s[256];
    int tid = threadIdx.x;
    int i = blockIdx.x * 256 + tid;
    int v = (i < NN) ? cnt[i] : 0;
    s[tid] = v;
    __syncthreads();
    for (int off = 1; off < 256; off <<= 1) {
        int t = (tid >= off) ? s[tid - off] : 0;
        __syncthreads();
        s[tid] += t;
        __syncthreads();
    }
    if (i < NN) rowptr[i] = s[tid] - v;
    if (tid == 255) bsum[blockIdx.x] = s[255];
}

__global__ void scan2(int* __restrict__ bsum, int nblocks) {
    __shared__ int s[256];
    int tid = threadIdx.x;
    int v = (tid < nblocks) ? bsum[tid] : 0;
    s[tid] = v;
    __syncthreads();
    for (int off = 1; off < 256; off <<= 1) {
        int t = (tid >= off) ? s[tid - off] : 0;
        __syncthreads();
        s[tid] += t;
        __syncthreads();
    }
    if (tid < nblocks) bsum[tid] = s[tid] - v;
}

__global__ void scan3(int* __restrict__ rowptr, const int* __restrict__ bsum,
                      int* __restrict__ fillpos) {
    int i = blockIdx.x * 256 + threadIdx.x;
    if (i < NN) {
        int r = rowptr[i] + bsum[blockIdx.x];
        rowptr[i] = r;
        fillpos[i] = r;
        if (i == NN - 1) rowptr[NN] = NE;
    }
}

// ---------------- XCD-local CSR fill ----------------
__global__ void __launch_bounds__(256)
fill_csr2(const int* __restrict__ ebuf, const int* __restrict__ flag,
          int* __restrict__ fillpos, int* __restrict__ col) {
    int rng = blockIdx.x & 7;
    int lo = rng * (NN / 8), hi = lo + (NN / 8);
    int is64 = flag[0];
    int stride = (gridDim.x >> 3) * 256;
    for (int e = (blockIdx.x >> 3) * 256 + threadIdx.x; e < NE; e += stride) {
        int d = edge_at(ebuf, is64, NE + e);
        if (d >= lo && d < hi) {
            int s = edge_at(ebuf, is64, e);
            int p = atomicAdd(&fillpos[d], 1);
            col[p] = s;
        }
    }
}

// ---------------- x -> bf16 panels xp[8][NN][16] ----------------
__global__ void conv_x(const float* __restrict__ x, ushort* __restrict__ xp) {
    int i = blockIdx.x * 256 + threadIdx.x;
    if (i >= NN * K1P) return;
    int n = i >> 7, c = i & 127;
    ushort v = (c < INC) ? f2bf(x[(size_t)n * INC + c]) : (ushort)0;
    xp[((size_t)(c >> 4) * NN + n) * 16 + (c & 15)] = v;
}

// ---------------- weight decompose + transpose ----------------
__global__ void decomp_w1(const float* __restrict__ W, ushort* __restrict__ hi,
                          ushort* __restrict__ lo) {
    int i = blockIdx.x * 256 + threadIdx.x;   // 256*128
    int n = i >> 7, k = i & 127;
    float v = (k < INC) ? W[k * HID + n] : 0.f;
    ushort h = f2bf(v);
    hi[n * K1P + k] = h;
    lo[n * K1P + k] = f2bf(v - bf2f(h));
}

__global__ void decomp_w2(const float* __restrict__ W, ushort* __restrict__ hi,
                          ushort* __restrict__ lo) {
    int i = blockIdx.x * 256 + threadIdx.x;   // 256*256
    int n = i >> 8, k = i & 255;
    float v = W[k * HID + n];
    ushort h = f2bf(v);
    hi[n * HID + k] = h;
    lo[n * HID + k] = f2bf(v - bf2f(h));
}

// ---------------- layer-1 panel aggregate ----------------
// Panel p (XCD p): channels [16p,16p+16). 2-lane groups, 128 dsts/block.
// out[n] = dinv[n]*(sum_s dinv[s]*xb[s] + dinv[n]*x[n]) -> hi/lo bf16 [N][128]
__global__ void __launch_bounds__(256)
agg1p(const ushort* __restrict__ xp, const float* __restrict__ x,
      const float* __restrict__ dinv, const int* __restrict__ rowptr,
      const int* __restrict__ col, ushort* __restrict__ ohi, ushort* __restrict__ olo) {
    int p = blockIdx.x & 7;
    int nb = blockIdx.x >> 3;
    int tid = threadIdx.x;
    int g = tid >> 1, q = tid & 1;
    int n = nb * 128 + g;
    if (n >= NN) return;
    const ushort* panel = xp + (size_t)p * NN * 16 + q * 8;
    int beg = rowptr[n], end = rowptr[n + 1];
    float a0=0.f,a1=0.f,a2=0.f,a3=0.f,a4=0.f,a5=0.f,a6=0.f,a7=0.f;
    int j = beg;
    for (; j + 1 < end; j += 2) {
        int s0 = col[j], s1 = col[j + 1];
        float w0 = dinv[s0], w1 = dinv[s1];
        uint4 u0 = *(const uint4*)(panel + (size_t)s0 * 16);
        uint4 u1 = *(const uint4*)(panel + (size_t)s1 * 16);
        a0 += w0 * bflo(u0.x) + w1 * bflo(u1.x);
        a1 += w0 * bfhi(u0.x) + w1 * bfhi(u1.x);
        a2 += w0 * bflo(u0.y) + w1 * bflo(u1.y);
        a3 += w0 * bfhi(u0.y) + w1 * bfhi(u1.y);
        a4 += w0 * bflo(u0.z) + w1 * bflo(u1.z);
        a5 += w0 * bfhi(u0.z) + w1 * bfhi(u1.z);
        a6 += w0 * bflo(u0.w) + w1 * bflo(u1.w);
        a7 += w0 * bfhi(u0.w) + w1 * bfhi(u1.w);
    }
    if (j < end) {
        int s0 = col[j];
        float w0 = dinv[s0];
        uint4 u0 = *(const uint4*)(panel + (size_t)s0 * 16);
        a0 += w0 * bflo(u0.x); a1 += w0 * bfhi(u0.x);
        a2 += w0 * bflo(u0.y); a3 += w0 * bfhi(u0.y);
        a4 += w0 * bflo(u0.z); a5 += w0 * bfhi(u0.z);
        a6 += w0 * bflo(u0.w); a7 += w0 * bfhi(u0.w);
    }
    int cbase = p * 16 + q * 8;
    float dn = dinv[n];
    float acc[8] = {a0,a1,a2,a3,a4,a5,a6,a7};
    ushort hs[8], ls[8];
    #pragma unroll
    for (int i = 0; i < 8; ++i) {
        int ch = cbase + i;
        float self = (ch < INC) ? x[(size_t)n * INC + ch] : 0.f;
        float r = dn * (acc[i] + dn * self);
        ushort h = f2bf(r);
        hs[i] = h;
        ls[i] = f2bf(r - bf2f(h));
    }
    *(uint4*)(ohi + (size_t)n * K1P + cbase) = *(uint4*)hs;
    *(uint4*)(olo + (size_t)n * K1P + cbase) = *(uint4*)ls;
}

// ---------------- layer-2 panel aggregate ----------------
// Panel p (XCD p): channels [32p,32p+32). 4-lane groups, 64 dsts/block.
__global__ void __launch_bounds__(256)
agg2p(const ushort* __restrict__ h1p, const float* __restrict__ dinv,
      const int* __restrict__ rowptr, const int* __restrict__ col,
      ushort* __restrict__ ohi, ushort* __restrict__ olo) {
    int p = blockIdx.x & 7;
    int nb = blockIdx.x >> 3;
    int tid = threadIdx.x;
    int g = tid >> 2, q = tid & 3;
    int n = nb * 64 + g;
    if (n >= NN) return;
    const ushort* panel = h1p + (size_t)p * NN * 32 + q * 8;
    int beg = rowptr[n], end = rowptr[n + 1];
    float a0=0.f,a1=0.f,a2=0.f,a3=0.f,a4=0.f,a5=0.f,a6=0.f,a7=0.f;
    int j = beg;
    for (; j + 1 < end; j += 2) {
        int s0 = col[j], s1 = col[j + 1];
        float w0 = dinv[s0], w1 = dinv[s1];
        uint4 u0 = *(const uint4*)(panel + (size_t)s0 * 32);
        uint4 u1 = *(const uint4*)(panel + (size_t)s1 * 32);
        a0 += w0 * bflo(u0.x) + w1 * bflo(u1.x);
        a1 += w0 * bfhi(u0.x) + w1 * bfhi(u1.x);
        a2 += w0 * bflo(u0.y) + w1 * bflo(u1.y);
        a3 += w0 * bfhi(u0.y) + w1 * bfhi(u1.y);
        a4 += w0 * bflo(u0.z) + w1 * bflo(u1.z);
        a5 += w0 * bfhi(u0.z) + w1 * bfhi(u1.z);
        a6 += w0 * bflo(u0.w) + w1 * bflo(u1.w);
        a7 += w0 * bfhi(u0.w) + w1 * bfhi(u1.w);
    }
    if (j < end) {
        int s0 = col[j];
        float w0 = dinv[s0];
        uint4 u0 = *(const uint4*)(panel + (size_t)s0 * 32);
        a0 += w0 * bflo(u0.x); a1 += w0 * bfhi(u0.x);
        a2 += w0 * bflo(u0.y); a3 += w0 * bfhi(u0.y);
        a4 += w0 * bflo(u0.z); a5 += w0 * bfhi(u0.z);
        a6 += w0 * bflo(u0.w); a7 += w0 * bfhi(u0.w);
    }
    float dn = dinv[n];
    uint4 us = *(const uint4*)(panel + (size_t)n * 32);   // bf16 self (same as before)
    float self[8] = {bflo(us.x),bfhi(us.x),bflo(us.y),bfhi(us.y),
                     bflo(us.z),bfhi(us.z),bflo(us.w),bfhi(us.w)};
    float acc[8] = {a0,a1,a2,a3,a4,a5,a6,a7};
    ushort hs[8], ls[8];
    #pragma unroll
    for (int i = 0; i < 8; ++i) {
        float r = dn * (acc[i] + dn * self[i]);
        ushort h = f2bf(r);
        hs[i] = h;
        ls[i] = f2bf(r - bf2f(h));
    }
    int cbase = p * 32 + q * 8;
    *(uint4*)(ohi + (size_t)n * HID + cbase) = *(uint4*)hs;
    *(uint4*)(olo + (size_t)n * HID + cbase) = *(uint4*)ls;
}

// ---------------- MFMA GEMM, split-bf16 fp32 emulation -----------------------
// MODE 1: h1p[ch>>5][row][ch&31] = bf16( relu(A@Bt + bias) )   (panel layout)
// MODE 2: fused layer-3: v = relu(A@Bt + bias); atomicAdd hw3[row] += v @ W3
template <int MODE>
__global__ void __launch_bounds__(256)
gemm_mfma(const ushort* __restrict__ Ahi, const ushort* __restrict__ Alo,
          const ushort* __restrict__ Bhi, const ushort* __restrict__ Blo,
          const float* __restrict__ bias, ushort* __restrict__ Cb,
          const float* __restrict__ W3, float* __restrict__ hw3,
          int M, int K, int Nn) {
    constexpr int BM = 128, BN = 128, BK = 32, LDK = BK + 8;
    __shared__ ushort sAh[BM * LDK], sAl[BM * LDK];
    __shared__ ushort sBh[BN * LDK], sBl[BN * LDK];
    int tid = threadIdx.x;
    int w = tid >> 6, l = tid & 63;
    int wr = w >> 1, wc = w & 1;
    int bm = blockIdx.x * BM, bn = blockIdx.y * BN;
    int l15 = l & 15, kg = l >> 4;
    f32x4 zero = {0.f, 0.f, 0.f, 0.f};
    f32x4 acc[4][4];
    #pragma unroll
    for (int i = 0; i < 4; ++i)
        #pragma unroll
        for (int j = 0; j < 4; ++j) acc[i][j] = zero;

    for (int kb = 0; kb < K; kb += BK) {
        #pragma unroll
        for (int it = 0; it < 2; ++it) {
            int cc = tid + it * 256;
            int row = cc >> 2, kp = (cc & 3) * 8;
            int ar = bm + row;
            float4 z4 = make_float4(0.f, 0.f, 0.f, 0.f);
            float4 avh = z4, avl = z4;
            if (ar < M) {
                avh = *(const float4*)(Ahi + (size_t)ar * K + kb + kp);
                avl = *(const float4*)(Alo + (size_t)ar * K + kb + kp);
            }
            *(float4*)&sAh[row * LDK + kp] = avh;
            *(float4*)&sAl[row * LDK + kp] = avl;
            int br = bn + row;  // Nn == 256 always covers
            float4 bvh = *(const float4*)(Bhi + (size_t)br * K + kb + kp);
            float4 bvl = *(const float4*)(Blo + (size_t)br * K + kb + kp);
            *(float4*)&sBh[row * LDK + kp] = bvh;
            *(float4*)&sBl[row * LDK + kp] = bvl;
        }
        __syncthreads();
        s16x8 ah[4], al[4], bh[4], bl[4];
        #pragma unroll
        for (int i = 0; i < 4; ++i) {
            int arow = wr * 64 + i * 16 + l15;
            ah[i] = *(const s16x8*)&sAh[arow * LDK + kg * 8];
            al[i] = *(const s16x8*)&sAl[arow * LDK + kg * 8];
            int brow = wc * 64 + i * 16 + l15;
            bh[i] = *(const s16x8*)&sBh[brow * LDK + kg * 8];
            bl[i] = *(const s16x8*)&sBl[brow * LDK + kg * 8];
        }
        #pragma unroll
        for (int i = 0; i < 4; ++i)
            #pragma unroll
            for (int j = 0; j < 4; ++j) {
                acc[i][j] = __builtin_amdgcn_mfma_f32_16x16x32_bf16(ah[i], bh[j], acc[i][j], 0, 0, 0);
                acc[i][j] = __builtin_amdgcn_mfma_f32_16x16x32_bf16(ah[i], bl[j], acc[i][j], 0, 0, 0);
                acc[i][j] = __builtin_amdgcn_mfma_f32_16x16x32_bf16(al[i], bh[j], acc[i][j], 0, 0, 0);
            }
        __syncthreads();
    }
    // C/D layout: col = l&15, row = (l>>4)*4 + r
    if (MODE == 1) {
        #pragma unroll
        for (int j = 0; j < 4; ++j) {
            int cn = bn + wc * 64 + j * 16 + l15;
            float bv = bias[cn];
            size_t pbase = ((size_t)(cn >> 5) * NN) * 32 + (cn & 31);
            #pragma unroll
            for (int i = 0; i < 4; ++i) {
                int rbase = bm + wr * 64 + i * 16 + kg * 4;
                #pragma unroll
                for (int r = 0; r < 4; ++r) {
                    int rm = rbase + r;
                    if (rm < M) {
                        float v = fmaxf(acc[i][j][r] + bv, 0.f);
                        Cb[pbase + (size_t)rm * 32] = f2bf(v);
                    }
                }
            }
        }
    } else {
        float p0[4][4], p1[4][4];
        #pragma unroll
        for (int i = 0; i < 4; ++i)
            #pragma unroll
            for (int r = 0; r < 4; ++r) { p0[i][r] = 0.f; p1[i][r] = 0.f; }
        #pragma unroll
        for (int j = 0; j < 4; ++j) {
            int cn = bn + wc * 64 + j * 16 + l15;
            float bv = bias[cn];
            float w30 = W3[cn * 2 + 0], w31 = W3[cn * 2 + 1];
            #pragma unroll
            for (int i = 0; i < 4; ++i)
                #pragma unroll
                for (int r = 0; r < 4; ++r) {
                    float v = fmaxf(acc[i][j][r] + bv, 0.f);
                    p0[i][r] += v * w30;
                    p1[i][r] += v * w31;
                }
        }
        #pragma unroll
        for (int i = 0; i < 4; ++i)
            #pragma unroll
            for (int r = 0; r < 4; ++r) {
                float q0 = p0[i][r], q1 = p1[i][r];
                #pragma unroll
                for (int off = 1; off < 16; off <<= 1) {
                    q0 += __shfl_xor(q0, off);
                    q1 += __shfl_xor(q1, off);
                }
                if (l15 == 0) {
                    int rm = bm + wr * 64 + i * 16 + kg * 4 + r;
                    if (rm < M) {
                        atomicAdd(&hw3[rm * 2 + 0], q0);
                        atomicAdd(&hw3[rm * 2 + 1], q1);
                    }
                }
            }
    }
}

// ---------------- layer-3 aggregation (2 channels) ---------------------------
__global__ void agg3(const float* __restrict__ hw3, const float* __restrict__ dinv,
                     const int* __restrict__ rowptr, const int* __restrict__ col,
                     const float* __restrict__ b3, float* __restrict__ out) {
    int n = blockIdx.x * blockDim.x + threadIdx.x;
    if (n >= NN) return;
    float a0 = 0.f, a1 = 0.f;
    int beg = rowptr[n], end = rowptr[n + 1];
    for (int j = beg; j < end; ++j) {
        int s = col[j];
        float w = dinv[s];
        float2 v = ((const float2*)hw3)[s];
        a0 += w * v.x;
        a1 += w * v.y;
    }
    float dn = dinv[n];
    float2 sv = ((const float2*)hw3)[n];
    out[n * 2 + 0] = dn * (a0 + dn * sv.x) + b3[0];
    out[n * 2 + 1] = dn * (a1 + dn * sv.y) + b3[1];
}

extern "C" void kernel_launch(void* const* d_in, const int* in_sizes, int n_in,
                              void* d_out, int out_size, void* d_ws, size_t ws_size,
                              hipStream_t stream) {
    const float* x   = (const float*)d_in[0];
    const int*   ebf = (const int*)d_in[1];
    const float* W1  = (const float*)d_in[2];
    const float* b1  = (const float*)d_in[3];
    const float* W2  = (const float*)d_in[4];
    const float* b2  = (const float*)d_in[5];
    const float* W3  = (const float*)d_in[6];
    const float* b3  = (const float*)d_in[7];
    float* out = (float*)d_out;

    char* ws = (char*)d_ws;
    size_t off = 0;
    auto carve = [&](size_t bytes) -> char* {
        char* p = ws + off;
        off += (bytes + 255) & ~(size_t)255;
        return p;
    };
    int*    flag   = (int*)   carve(256);
    int*    cnt    = (int*)   carve((size_t)NN * 4);
    float*  dinv   = (float*) carve((size_t)NN * 4);
    int*    rowptr = (int*)   carve((size_t)(NN + 1) * 4);
    int*    fillpos= (int*)   carve((size_t)NN * 4);
    int*    bsum   = (int*)   carve(256 * 4);
    int*    col    = (int*)   carve((size_t)NE * 4);
    ushort* xp     = (ushort*)carve((size_t)NN * K1P * 2);     // 8 panels [NN][16]
    ushort* W1thi  = (ushort*)carve((size_t)HID * K1P * 2);
    ushort* W1tlo  = (ushort*)carve((size_t)HID * K1P * 2);
    ushort* W2thi  = (ushort*)carve((size_t)HID * HID * 2);
    ushort* W2tlo  = (ushort*)carve((size_t)HID * HID * 2);
    ushort* a1hi   = (ushort*)carve((size_t)NN * K1P * 2);
    ushort* a1lo   = (ushort*)carve((size_t)NN * K1P * 2);
    ushort* h1p    = (ushort*)carve((size_t)NN * HID * 2);     // 8 panels [NN][32]
    ushort* a2hi   = (ushort*)carve((size_t)NN * HID * 2);
    ushort* a2lo   = (ushort*)carve((size_t)NN * HID * 2);
    float*  hw3    = (float*) carve((size_t)NN * OUTC * 4);
    (void)ws_size; (void)n_in; (void)in_sizes; (void)out_size;

    const int SCAN_G = (NN + 255) / 256;

    hipMemsetAsync(cnt, 0, (size_t)NN * 4, stream);
    hipMemsetAsync(hw3, 0, (size_t)NN * OUTC * 4, stream);
    detect_fmt<<<1, 64, 0, stream>>>(ebf, flag);
    deg_hist2<<<2048, 256, 0, stream>>>(ebf, flag, cnt);
    dinv_kernel<<<SCAN_G, 256, 0, stream>>>(cnt, dinv);
    scan1<<<SCAN_G, 256, 0, stream>>>(cnt, rowptr, bsum);
    scan2<<<1, 256, 0, stream>>>(bsum, SCAN_G);
    scan3<<<SCAN_G, 256, 0, stream>>>(rowptr, bsum, fillpos);
    fill_csr2<<<2048, 256, 0, stream>>>(ebf, flag, fillpos, col);
    conv_x<<<((size_t)NN * K1P + 255) / 256, 256, 0, stream>>>(x, xp);
    decomp_w1<<<(HID * K1P) / 256, 256, 0, stream>>>(W1, W1thi, W1tlo);
    decomp_w2<<<(HID * HID) / 256, 256, 0, stream>>>(W2, W2thi, W2tlo);

    // layer 1: panel-gather aggregate x, MFMA 128->256 + relu -> h1 panels
    agg1p<<<8 * ((NN + 127) / 128), 256, 0, stream>>>(xp, x, dinv, rowptr, col, a1hi, a1lo);
    {
        dim3 g((NN + 127) / 128, HID / 128);
        gemm_mfma<1><<<g, 256, 0, stream>>>(a1hi, a1lo, W1thi, W1tlo, b1, h1p,
                                            nullptr, nullptr, NN, K1P, HID);
    }
    // layer 2: panel-gather aggregate h1, MFMA 256->256 + relu, fused @W3 -> hw3
    agg2p<<<8 * ((NN + 63) / 64), 256, 0, stream>>>(h1p, dinv, rowptr, col, a2hi, a2lo);
    {
        dim3 g((NN + 127) / 128, HID / 128);
        gemm_mfma<2><<<g, 256, 0, stream>>>(a2hi, a2lo, W2thi, W2tlo, b2, nullptr,
                                            W3, hw3, NN, HID, HID);
    }
    // layer 3: 2-channel aggregation + bias
    agg3<<<SCAN_G, 256, 0, stream>>>(hw3, dinv, rowptr, col, b3, out);
}

// Round 7
// 569.573 us; speedup vs baseline: 1.2139x; 1.2139x over previous
//
#include <hip/hip_runtime.h>
#include <hip/hip_bf16.h>
#include <stdint.h>

#define NN 50000
#define NE 1600000
#define INC 116
#define XBP 128     // bf16-padded x row stride
#define K1P 128
#define HID 256
#define OUTC 2
#define NT 13       // source tiles of 4096 nodes (50000 -> 13 tiles)
#define TSH 12      // tile(s) = s >> 12

typedef float f32x4 __attribute__((ext_vector_type(4)));
typedef short s16x8 __attribute__((ext_vector_type(8)));

__device__ __forceinline__ ushort f2bf(float v) {
    uint32_t u = __float_as_uint(v);
    return (ushort)((u + 0x7FFFu + ((u >> 16) & 1u)) >> 16);
}
__device__ __forceinline__ float bf2f(ushort b) {
    return __uint_as_float(((uint32_t)b) << 16);
}
__device__ __forceinline__ float bflo(uint32_t u) { return __uint_as_float(u << 16); }
__device__ __forceinline__ float bfhi(uint32_t u) { return __uint_as_float(u & 0xFFFF0000u); }

// ---------------- edge-index format hedge (int32 vs int64) ----------------
__global__ void detect_fmt(const int* __restrict__ ebuf, int* __restrict__ flag) {
    int v = ebuf[2 * threadIdx.x + 1];
    unsigned long long b = __ballot(v != 0);
    if (threadIdx.x == 0) flag[0] = (b == 0ULL) ? 1 : 0;
}

__device__ __forceinline__ int edge_at(const int* __restrict__ ebuf, int is64, int idx) {
    return is64 ? ebuf[2 * idx] : ebuf[idx];
}

// ---------------- (dst, src-tile) histogram, XCD-local dst ranges ----------
__global__ void __launch_bounds__(256)
deg_hist3(const int* __restrict__ ebuf, const int* __restrict__ flag,
          int* __restrict__ cnt2) {
    int rng = blockIdx.x & 7;
    int lo = rng * (NN / 8), hi = lo + (NN / 8);
    int is64 = flag[0];
    int stride = (gridDim.x >> 3) * 256;
    for (int e = (blockIdx.x >> 3) * 256 + threadIdx.x; e < NE; e += stride) {
        int d = edge_at(ebuf, is64, NE + e);
        if (d >= lo && d < hi) {
            int s = edge_at(ebuf, is64, e);
            atomicAdd(&cnt2[d * NT + (s >> TSH)], 1);
        }
    }
}

// per-node totals + dinv
__global__ void sum_cnt(const int* __restrict__ cnt2, int* __restrict__ cnt,
                        float* __restrict__ dinv) {
    int n = blockIdx.x * 256 + threadIdx.x;
    if (n >= NN) return;
    int s = 0;
    #pragma unroll
    for (int t = 0; t < NT; ++t) s += cnt2[n * NT + t];
    cnt[n] = s;
    dinv[n] = rsqrtf((float)s + 1.0f);
}

// ---------------- prefix scan over per-node totals ----------------
__global__ void scan1(const int* __restrict__ cnt, int* __restrict__ rowptr,
                      int* __restrict__ bsum) {
    __shared__ int s[256];
    int tid = threadIdx.x;
    int i = blockIdx.x * 256 + tid;
    int v = (i < NN) ? cnt[i] : 0;
    s[tid] = v;
    __syncthreads();
    for (int off = 1; off < 256; off <<= 1) {
        int t = (tid >= off) ? s[tid - off] : 0;
        __syncthreads();
        s[tid] += t;
        __syncthreads();
    }
    if (i < NN) rowptr[i] = s[tid] - v;
    if (tid == 255) bsum[blockIdx.x] = s[255];
}

__global__ void scan2(int* __restrict__ bsum, int nblocks) {
    __shared__ int s[256];
    int tid = threadIdx.x;
    int v = (tid < nblocks) ? bsum[tid] : 0;
    s[tid] = v;
    __syncthreads();
    for (int off = 1; off < 256; off <<= 1) {
        int t = (tid >= off) ? s[tid - off] : 0;
        __syncthreads();
        s[tid] += t;
        __syncthreads();
    }
    if (tid < nblocks) bsum[tid] = s[tid] - v;
}

__global__ void scan3(int* __restrict__ rowptr, const int* __restrict__ bsum) {
    int i = blockIdx.x * 256 + threadIdx.x;
    if (i < NN) {
        rowptr[i] += bsum[blockIdx.x];
        if (i == NN - 1) rowptr[NN] = NE;
    }
}

// rp2[n][t] = rowptr[n] + prefix_t(cnt2[n][*]); fillpos2 = copy
__global__ void mk_rowptr2(const int* __restrict__ rowptr, const int* __restrict__ cnt2,
                           int* __restrict__ rp2, int* __restrict__ fillpos2) {
    int n = blockIdx.x * 256 + threadIdx.x;
    if (n >= NN) return;
    int running = rowptr[n];
    #pragma unroll
    for (int t = 0; t < NT; ++t) {
        rp2[n * NT + t] = running;
        fillpos2[n * NT + t] = running;
        running += cnt2[n * NT + t];
    }
    if (n == NN - 1) rp2[NN * NT] = NE;
}

// ---------------- XCD-local CSR fill, tile-bucketed ----------------
__global__ void __launch_bounds__(256)
fill_csr3(const int* __restrict__ ebuf, const int* __restrict__ flag,
          int* __restrict__ fillpos2, int* __restrict__ col) {
    int rng = blockIdx.x & 7;
    int lo = rng * (NN / 8), hi = lo + (NN / 8);
    int is64 = flag[0];
    int stride = (gridDim.x >> 3) * 256;
    for (int e = (blockIdx.x >> 3) * 256 + threadIdx.x; e < NE; e += stride) {
        int d = edge_at(ebuf, is64, NE + e);
        if (d >= lo && d < hi) {
            int s = edge_at(ebuf, is64, e);
            int p = atomicAdd(&fillpos2[d * NT + (s >> TSH)], 1);
            col[p] = s;
        }
    }
}

// ---------------- x -> bf16 row-major [NN][128] ----------------
__global__ void conv_x(const float* __restrict__ x, ushort* __restrict__ xb) {
    int i = blockIdx.x * 256 + threadIdx.x;
    if (i >= NN * XBP) return;
    int n = i >> 7, c = i & 127;
    xb[i] = (c < INC) ? f2bf(x[(size_t)n * INC + c]) : (ushort)0;
}

// ---------------- weight decompose + transpose ----------------
__global__ void decomp_w1(const float* __restrict__ W, ushort* __restrict__ hi,
                          ushort* __restrict__ lo) {
    int i = blockIdx.x * 256 + threadIdx.x;   // 256*128
    int n = i >> 7, k = i & 127;
    float v = (k < INC) ? W[k * HID + n] : 0.f;
    ushort h = f2bf(v);
    hi[n * K1P + k] = h;
    lo[n * K1P + k] = f2bf(v - bf2f(h));
}

__global__ void decomp_w2(const float* __restrict__ W, ushort* __restrict__ hi,
                          ushort* __restrict__ lo) {
    int i = blockIdx.x * 256 + threadIdx.x;   // 256*256
    int n = i >> 8, k = i & 255;
    float v = W[k * HID + n];
    ushort h = f2bf(v);
    hi[n * HID + k] = h;
    lo[n * HID + k] = f2bf(v - bf2f(h));
}

// ---------------- layer-1 source-tiled aggregate ----------------
// 16 groups x 16 lanes; group owns 2 nodes; lane c = 16B chunk (8 ch).
// Tiles outermost: all blocks sweep the same 1MB source window together.
__global__ void __launch_bounds__(256)
agg1t(const ushort* __restrict__ xb, const float* __restrict__ x,
      const float* __restrict__ dinv, const int* __restrict__ rp2,
      const int* __restrict__ col, ushort* __restrict__ ohi, ushort* __restrict__ olo) {
    int tid = threadIdx.x;
    int g = tid >> 4, c = tid & 15;
    int nbase = blockIdx.x * 32 + g * 2;
    const ushort* hc = xb + c * 8;
    float acc[2][8];
    #pragma unroll
    for (int i = 0; i < 2; ++i)
        #pragma unroll
        for (int k = 0; k < 8; ++k) acc[i][k] = 0.f;
    for (int t = 0; t < NT; ++t) {
        #pragma unroll
        for (int i = 0; i < 2; ++i) {
            int n = nbase + i;
            if (n < NN) {
                int beg = rp2[n * NT + t], end = rp2[n * NT + t + 1];
                int j = beg;
                for (; j + 1 < end; j += 2) {
                    int s0 = col[j], s1 = col[j + 1];
                    float w0 = dinv[s0], w1 = dinv[s1];
                    uint4 u0 = *(const uint4*)(hc + (size_t)s0 * XBP);
                    uint4 u1 = *(const uint4*)(hc + (size_t)s1 * XBP);
                    acc[i][0] += w0 * bflo(u0.x) + w1 * bflo(u1.x);
                    acc[i][1] += w0 * bfhi(u0.x) + w1 * bfhi(u1.x);
                    acc[i][2] += w0 * bflo(u0.y) + w1 * bflo(u1.y);
                    acc[i][3] += w0 * bfhi(u0.y) + w1 * bfhi(u1.y);
                    acc[i][4] += w0 * bflo(u0.z) + w1 * bflo(u1.z);
                    acc[i][5] += w0 * bfhi(u0.z) + w1 * bfhi(u1.z);
                    acc[i][6] += w0 * bflo(u0.w) + w1 * bflo(u1.w);
                    acc[i][7] += w0 * bfhi(u0.w) + w1 * bfhi(u1.w);
                }
                if (j < end) {
                    int s0 = col[j];
                    float w0 = dinv[s0];
                    uint4 u0 = *(const uint4*)(hc + (size_t)s0 * XBP);
                    acc[i][0] += w0 * bflo(u0.x); acc[i][1] += w0 * bfhi(u0.x);
                    acc[i][2] += w0 * bflo(u0.y); acc[i][3] += w0 * bfhi(u0.y);
                    acc[i][4] += w0 * bflo(u0.z); acc[i][5] += w0 * bfhi(u0.z);
                    acc[i][6] += w0 * bflo(u0.w); acc[i][7] += w0 * bfhi(u0.w);
                }
            }
        }
        __syncthreads();
    }
    #pragma unroll
    for (int i = 0; i < 2; ++i) {
        int n = nbase + i;
        if (n >= NN) continue;
        float dn = dinv[n];
        ushort hs[8], ls[8];
        #pragma unroll
        for (int k = 0; k < 8; ++k) {
            int ch = c * 8 + k;
            float self = (ch < INC) ? x[(size_t)n * INC + ch] : 0.f;
            float r = dn * (acc[i][k] + dn * self);
            ushort h = f2bf(r);
            hs[k] = h;
            ls[k] = f2bf(r - bf2f(h));
        }
        *(uint4*)(ohi + (size_t)n * K1P + c * 8) = *(uint4*)hs;
        *(uint4*)(olo + (size_t)n * K1P + c * 8) = *(uint4*)ls;
    }
}

// ---------------- layer-2 source-tiled aggregate ----------------
// 8 groups x 32 lanes; group owns 4 nodes; lane c = 16B chunk (8 ch).
__global__ void __launch_bounds__(256)
agg2t(const ushort* __restrict__ hb, const float* __restrict__ dinv,
      const int* __restrict__ rp2, const int* __restrict__ col,
      ushort* __restrict__ ohi, ushort* __restrict__ olo) {
    int tid = threadIdx.x;
    int g = tid >> 5, c = tid & 31;
    int nbase = blockIdx.x * 32 + g * 4;
    const ushort* hc = hb + c * 8;
    float acc[4][8];
    #pragma unroll
    for (int i = 0; i < 4; ++i)
        #pragma unroll
        for (int k = 0; k < 8; ++k) acc[i][k] = 0.f;
    for (int t = 0; t < NT; ++t) {
        #pragma unroll
        for (int i = 0; i < 4; ++i) {
            int n = nbase + i;
            if (n < NN) {
                int beg = rp2[n * NT + t], end = rp2[n * NT + t + 1];
                int j = beg;
                for (; j + 1 < end; j += 2) {
                    int s0 = col[j], s1 = col[j + 1];
                    float w0 = dinv[s0], w1 = dinv[s1];
                    uint4 u0 = *(const uint4*)(hc + (size_t)s0 * HID);
                    uint4 u1 = *(const uint4*)(hc + (size_t)s1 * HID);
                    acc[i][0] += w0 * bflo(u0.x) + w1 * bflo(u1.x);
                    acc[i][1] += w0 * bfhi(u0.x) + w1 * bfhi(u1.x);
                    acc[i][2] += w0 * bflo(u0.y) + w1 * bflo(u1.y);
                    acc[i][3] += w0 * bfhi(u0.y) + w1 * bfhi(u1.y);
                    acc[i][4] += w0 * bflo(u0.z) + w1 * bflo(u1.z);
                    acc[i][5] += w0 * bfhi(u0.z) + w1 * bfhi(u1.z);
                    acc[i][6] += w0 * bflo(u0.w) + w1 * bflo(u1.w);
                    acc[i][7] += w0 * bfhi(u0.w) + w1 * bfhi(u1.w);
                }
                if (j < end) {
                    int s0 = col[j];
                    float w0 = dinv[s0];
                    uint4 u0 = *(const uint4*)(hc + (size_t)s0 * HID);
                    acc[i][0] += w0 * bflo(u0.x); acc[i][1] += w0 * bfhi(u0.x);
                    acc[i][2] += w0 * bflo(u0.y); acc[i][3] += w0 * bfhi(u0.y);
                    acc[i][4] += w0 * bflo(u0.z); acc[i][5] += w0 * bfhi(u0.z);
                    acc[i][6] += w0 * bflo(u0.w); acc[i][7] += w0 * bfhi(u0.w);
                }
            }
        }
        __syncthreads();
    }
    #pragma unroll
    for (int i = 0; i < 4; ++i) {
        int n = nbase + i;
        if (n >= NN) continue;
        float dn = dinv[n];
        uint4 us = *(const uint4*)(hc + (size_t)n * HID);
        float self[8] = {bflo(us.x),bfhi(us.x),bflo(us.y),bfhi(us.y),
                         bflo(us.z),bfhi(us.z),bflo(us.w),bfhi(us.w)};
        ushort hs[8], ls[8];
        #pragma unroll
        for (int k = 0; k < 8; ++k) {
            float r = dn * (acc[i][k] + dn * self[k]);
            ushort h = f2bf(r);
            hs[k] = h;
            ls[k] = f2bf(r - bf2f(h));
        }
        *(uint4*)(ohi + (size_t)n * HID + c * 8) = *(uint4*)hs;
        *(uint4*)(olo + (size_t)n * HID + c * 8) = *(uint4*)ls;
    }
}

// ---------------- MFMA GEMM, split-bf16 fp32 emulation -----------------------
// MODE 1: C = bf16( relu(A@Bt + bias) ) row-major   (layer 1 -> h1b)
// MODE 2: fused layer-3: v = relu(A@Bt + bias); atomicAdd hw3[row] += v @ W3
template <int MODE>
__global__ void __launch_bounds__(256)
gemm_mfma(const ushort* __restrict__ Ahi, const ushort* __restrict__ Alo,
          const ushort* __restrict__ Bhi, const ushort* __restrict__ Blo,
          const float* __restrict__ bias, ushort* __restrict__ Cb,
          const float* __restrict__ W3, float* __restrict__ hw3,
          int M, int K, int Nn) {
    constexpr int BM = 128, BN = 128, BK = 32, LDK = BK + 8;
    __shared__ ushort sAh[BM * LDK], sAl[BM * LDK];
    __shared__ ushort sBh[BN * LDK], sBl[BN * LDK];
    int tid = threadIdx.x;
    int w = tid >> 6, l = tid & 63;
    int wr = w >> 1, wc = w & 1;
    int bm = blockIdx.x * BM, bn = blockIdx.y * BN;
    int l15 = l & 15, kg = l >> 4;
    f32x4 zero = {0.f, 0.f, 0.f, 0.f};
    f32x4 acc[4][4];
    #pragma unroll
    for (int i = 0; i < 4; ++i)
        #pragma unroll
        for (int j = 0; j < 4; ++j) acc[i][j] = zero;

    for (int kb = 0; kb < K; kb += BK) {
        #pragma unroll
        for (int it = 0; it < 2; ++it) {
            int cc = tid + it * 256;
            int row = cc >> 2, kp = (cc & 3) * 8;
            int ar = bm + row;
            float4 z4 = make_float4(0.f, 0.f, 0.f, 0.f);
            float4 avh = z4, avl = z4;
            if (ar < M) {
                avh = *(const float4*)(Ahi + (size_t)ar * K + kb + kp);
                avl = *(const float4*)(Alo + (size_t)ar * K + kb + kp);
            }
            *(float4*)&sAh[row * LDK + kp] = avh;
            *(float4*)&sAl[row * LDK + kp] = avl;
            int br = bn + row;  // Nn == 256 always covers
            float4 bvh = *(const float4*)(Bhi + (size_t)br * K + kb + kp);
            float4 bvl = *(const float4*)(Blo + (size_t)br * K + kb + kp);
            *(float4*)&sBh[row * LDK + kp] = bvh;
            *(float4*)&sBl[row * LDK + kp] = bvl;
        }
        __syncthreads();
        s16x8 ah[4], al[4], bh[4], bl[4];
        #pragma unroll
        for (int i = 0; i < 4; ++i) {
            int arow = wr * 64 + i * 16 + l15;
            ah[i] = *(const s16x8*)&sAh[arow * LDK + kg * 8];
            al[i] = *(const s16x8*)&sAl[arow * LDK + kg * 8];
            int brow = wc * 64 + i * 16 + l15;
            bh[i] = *(const s16x8*)&sBh[brow * LDK + kg * 8];
            bl[i] = *(const s16x8*)&sBl[brow * LDK + kg * 8];
        }
        #pragma unroll
        for (int i = 0; i < 4; ++i)
            #pragma unroll
            for (int j = 0; j < 4; ++j) {
                acc[i][j] = __builtin_amdgcn_mfma_f32_16x16x32_bf16(ah[i], bh[j], acc[i][j], 0, 0, 0);
                acc[i][j] = __builtin_amdgcn_mfma_f32_16x16x32_bf16(ah[i], bl[j], acc[i][j], 0, 0, 0);
                acc[i][j] = __builtin_amdgcn_mfma_f32_16x16x32_bf16(al[i], bh[j], acc[i][j], 0, 0, 0);
            }
        __syncthreads();
    }
    // C/D layout: col = l&15, row = (l>>4)*4 + r
    if (MODE == 1) {
        #pragma unroll
        for (int j = 0; j < 4; ++j) {
            int cn = bn + wc * 64 + j * 16 + l15;
            float bv = bias[cn];
            #pragma unroll
            for (int i = 0; i < 4; ++i) {
                int rbase = bm + wr * 64 + i * 16 + kg * 4;
                #pragma unroll
                for (int r = 0; r < 4; ++r) {
                    int rm = rbase + r;
                    if (rm < M) {
                        float v = fmaxf(acc[i][j][r] + bv, 0.f);
                        Cb[(size_t)rm * Nn + cn] = f2bf(v);
                    }
                }
            }
        }
    } else {
        float p0[4][4], p1[4][4];
        #pragma unroll
        for (int i = 0; i < 4; ++i)
            #pragma unroll
            for (int r = 0; r < 4; ++r) { p0[i][r] = 0.f; p1[i][r] = 0.f; }
        #pragma unroll
        for (int j = 0; j < 4; ++j) {
            int cn = bn + wc * 64 + j * 16 + l15;
            float bv = bias[cn];
            float w30 = W3[cn * 2 + 0], w31 = W3[cn * 2 + 1];
            #pragma unroll
            for (int i = 0; i < 4; ++i)
                #pragma unroll
                for (int r = 0; r < 4; ++r) {
                    float v = fmaxf(acc[i][j][r] + bv, 0.f);
                    p0[i][r] += v * w30;
                    p1[i][r] += v * w31;
                }
        }
        #pragma unroll
        for (int i = 0; i < 4; ++i)
            #pragma unroll
            for (int r = 0; r < 4; ++r) {
                float q0 = p0[i][r], q1 = p1[i][r];
                #pragma unroll
                for (int off = 1; off < 16; off <<= 1) {
                    q0 += __shfl_xor(q0, off);
                    q1 += __shfl_xor(q1, off);
                }
                if (l15 == 0) {
                    int rm = bm + wr * 64 + i * 16 + kg * 4 + r;
                    if (rm < M) {
                        atomicAdd(&hw3[rm * 2 + 0], q0);
                        atomicAdd(&hw3[rm * 2 + 1], q1);
                    }
                }
            }
    }
}

// ---------------- layer-3 aggregation (2 channels) ---------------------------
__global__ void agg3(const float* __restrict__ hw3, const float* __restrict__ dinv,
                     const int* __restrict__ rowptr, const int* __restrict__ col,
                     const float* __restrict__ b3, float* __restrict__ out) {
    int n = blockIdx.x * blockDim.x + threadIdx.x;
    if (n >= NN) return;
    float a0 = 0.f, a1 = 0.f;
    int beg = rowptr[n], end = rowptr[n + 1];
    for (int j = beg; j < end; ++j) {
        int s = col[j];
        float w = dinv[s];
        float2 v = ((const float2*)hw3)[s];
        a0 += w * v.x;
        a1 += w * v.y;
    }
    float dn = dinv[n];
    float2 sv = ((const float2*)hw3)[n];
    out[n * 2 + 0] = dn * (a0 + dn * sv.x) + b3[0];
    out[n * 2 + 1] = dn * (a1 + dn * sv.y) + b3[1];
}

extern "C" void kernel_launch(void* const* d_in, const int* in_sizes, int n_in,
                              void* d_out, int out_size, void* d_ws, size_t ws_size,
                              hipStream_t stream) {
    const float* x   = (const float*)d_in[0];
    const int*   ebf = (const int*)d_in[1];
    const float* W1  = (const float*)d_in[2];
    const float* b1  = (const float*)d_in[3];
    const float* W2  = (const float*)d_in[4];
    const float* b2  = (const float*)d_in[5];
    const float* W3  = (const float*)d_in[6];
    const float* b3  = (const float*)d_in[7];
    float* out = (float*)d_out;

    char* ws = (char*)d_ws;
    size_t off = 0;
    auto carve = [&](size_t bytes) -> char* {
        char* p = ws + off;
        off += (bytes + 255) & ~(size_t)255;
        return p;
    };
    int*    flag    = (int*)   carve(256);
    int*    cnt     = (int*)   carve((size_t)NN * 4);
    int*    cnt2    = (int*)   carve((size_t)NN * NT * 4);
    float*  dinv    = (float*) carve((size_t)NN * 4);
    int*    rowptr  = (int*)   carve((size_t)(NN + 1) * 4);
    int*    rp2     = (int*)   carve((size_t)(NN * NT + 1) * 4);
    int*    fillpos2= (int*)   carve((size_t)NN * NT * 4);
    int*    bsum    = (int*)   carve(256 * 4);
    int*    col     = (int*)   carve((size_t)NE * 4);
    ushort* xb      = (ushort*)carve((size_t)NN * XBP * 2);
    ushort* W1thi   = (ushort*)carve((size_t)HID * K1P * 2);
    ushort* W1tlo   = (ushort*)carve((size_t)HID * K1P * 2);
    ushort* W2thi   = (ushort*)carve((size_t)HID * HID * 2);
    ushort* W2tlo   = (ushort*)carve((size_t)HID * HID * 2);
    ushort* a1hi    = (ushort*)carve((size_t)NN * K1P * 2);
    ushort* a1lo    = (ushort*)carve((size_t)NN * K1P * 2);
    ushort* h1b     = (ushort*)carve((size_t)NN * HID * 2);
    ushort* a2hi    = (ushort*)carve((size_t)NN * HID * 2);
    ushort* a2lo    = (ushort*)carve((size_t)NN * HID * 2);
    float*  hw3     = (float*) carve((size_t)NN * OUTC * 4);
    (void)ws_size; (void)n_in; (void)in_sizes; (void)out_size;

    const int SCAN_G = (NN + 255) / 256;
    const int AGG_G  = (NN + 31) / 32;   // 1563 blocks, all co-resident

    hipMemsetAsync(cnt2, 0, (size_t)NN * NT * 4, stream);
    hipMemsetAsync(hw3, 0, (size_t)NN * OUTC * 4, stream);
    detect_fmt<<<1, 64, 0, stream>>>(ebf, flag);
    deg_hist3<<<2048, 256, 0, stream>>>(ebf, flag, cnt2);
    sum_cnt<<<SCAN_G, 256, 0, stream>>>(cnt2, cnt, dinv);
    scan1<<<SCAN_G, 256, 0, stream>>>(cnt, rowptr, bsum);
    scan2<<<1, 256, 0, stream>>>(bsum, SCAN_G);
    scan3<<<SCAN_G, 256, 0, stream>>>(rowptr, bsum);
    mk_rowptr2<<<SCAN_G, 256, 0, stream>>>(rowptr, cnt2, rp2, fillpos2);
    fill_csr3<<<2048, 256, 0, stream>>>(ebf, flag, fillpos2, col);
    conv_x<<<((size_t)NN * XBP + 255) / 256, 256, 0, stream>>>(x, xb);
    decomp_w1<<<(HID * K1P) / 256, 256, 0, stream>>>(W1, W1thi, W1tlo);
    decomp_w2<<<(HID * HID) / 256, 256, 0, stream>>>(W2, W2thi, W2tlo);

    // layer 1: source-tiled bf16 gather-aggregate x, MFMA 128->256 + relu -> bf16 h1
    agg1t<<<AGG_G, 256, 0, stream>>>(xb, x, dinv, rp2, col, a1hi, a1lo);
    {
        dim3 g((NN + 127) / 128, HID / 128);
        gemm_mfma<1><<<g, 256, 0, stream>>>(a1hi, a1lo, W1thi, W1tlo, b1, h1b,
                                            nullptr, nullptr, NN, K1P, HID);
    }
    // layer 2: source-tiled bf16 gather-aggregate h1, MFMA 256->256 + relu, fused @W3
    agg2t<<<AGG_G, 256, 0, stream>>>(h1b, dinv, rp2, col, a2hi, a2lo);
    {
        dim3 g((NN + 127) / 128, HID / 128);
        gemm_mfma<2><<<g, 256, 0, stream>>>(a2hi, a2lo, W2thi, W2tlo, b2, nullptr,
                                            W3, hw3, NN, HID, HID);
    }
    // layer 3: 2-channel aggregation + bias
    agg3<<<SCAN_G, 256, 0, stream>>>(hw3, dinv, rowptr, col, b3, out);
}

// Round 8
// 522.882 us; speedup vs baseline: 1.3223x; 1.0893x over previous
//
#include <hip/hip_runtime.h>
#include <hip/hip_bf16.h>
#include <stdint.h>

#define NN 50000
#define NE 1600000
#define INC 116
#define XBP 128     // bf16-padded x row stride (256B rows)
#define K1P 128
#define HID 256
#define OUTC 2
#define NT 13       // source tiles of 4096 nodes
#define TSH 12

typedef float f32x4 __attribute__((ext_vector_type(4)));
typedef short s16x8 __attribute__((ext_vector_type(8)));

__device__ __forceinline__ ushort f2bf(float v) {
    uint32_t u = __float_as_uint(v);
    return (ushort)((u + 0x7FFFu + ((u >> 16) & 1u)) >> 16);
}
__device__ __forceinline__ float bf2f(ushort b) {
    return __uint_as_float(((uint32_t)b) << 16);
}
__device__ __forceinline__ float bflo(uint32_t u) { return __uint_as_float(u << 16); }
__device__ __forceinline__ float bfhi(uint32_t u) { return __uint_as_float(u & 0xFFFF0000u); }

// ---------------- edge-index format hedge (int32 vs int64) ----------------
__global__ void detect_fmt(const int* __restrict__ ebuf, int* __restrict__ flag) {
    int v = ebuf[2 * threadIdx.x + 1];
    unsigned long long b = __ballot(v != 0);
    if (threadIdx.x == 0) flag[0] = (b == 0ULL) ? 1 : 0;
}

__device__ __forceinline__ int edge_at(const int* __restrict__ ebuf, int is64, int idx) {
    return is64 ? ebuf[2 * idx] : ebuf[idx];
}

// ---------------- (dst, src-tile) histogram, XCD-local dst ranges ----------
__global__ void __launch_bounds__(256)
deg_hist3(const int* __restrict__ ebuf, const int* __restrict__ flag,
          int* __restrict__ cnt2) {
    int rng = blockIdx.x & 7;
    int lo = rng * (NN / 8), hi = lo + (NN / 8);
    int is64 = flag[0];
    int stride = (gridDim.x >> 3) * 256;
    for (int e = (blockIdx.x >> 3) * 256 + threadIdx.x; e < NE; e += stride) {
        int d = edge_at(ebuf, is64, NE + e);
        if (d >= lo && d < hi) {
            int s = edge_at(ebuf, is64, e);
            atomicAdd(&cnt2[d * NT + (s >> TSH)], 1);
        }
    }
}

__global__ void sum_cnt(const int* __restrict__ cnt2, int* __restrict__ cnt,
                        float* __restrict__ dinv) {
    int n = blockIdx.x * 256 + threadIdx.x;
    if (n >= NN) return;
    int s = 0;
    #pragma unroll
    for (int t = 0; t < NT; ++t) s += cnt2[n * NT + t];
    cnt[n] = s;
    dinv[n] = rsqrtf((float)s + 1.0f);
}

// ---------------- prefix scan ----------------
__global__ void scan1(const int* __restrict__ cnt, int* __restrict__ rowptr,
                      int* __restrict__ bsum) {
    __shared__ int s[256];
    int tid = threadIdx.x;
    int i = blockIdx.x * 256 + tid;
    int v = (i < NN) ? cnt[i] : 0;
    s[tid] = v;
    __syncthreads();
    for (int off = 1; off < 256; off <<= 1) {
        int t = (tid >= off) ? s[tid - off] : 0;
        __syncthreads();
        s[tid] += t;
        __syncthreads();
    }
    if (i < NN) rowptr[i] = s[tid] - v;
    if (tid == 255) bsum[blockIdx.x] = s[255];
}

__global__ void scan2(int* __restrict__ bsum, int nblocks) {
    __shared__ int s[256];
    int tid = threadIdx.x;
    int v = (tid < nblocks) ? bsum[tid] : 0;
    s[tid] = v;
    __syncthreads();
    for (int off = 1; off < 256; off <<= 1) {
        int t = (tid >= off) ? s[tid - off] : 0;
        __syncthreads();
        s[tid] += t;
        __syncthreads();
    }
    if (tid < nblocks) bsum[tid] = s[tid] - v;
}

__global__ void scan3(int* __restrict__ rowptr, const int* __restrict__ bsum) {
    int i = blockIdx.x * 256 + threadIdx.x;
    if (i < NN) {
        rowptr[i] += bsum[blockIdx.x];
        if (i == NN - 1) rowptr[NN] = NE;
    }
}

__global__ void mk_rowptr2(const int* __restrict__ rowptr, const int* __restrict__ cnt2,
                           int* __restrict__ fillpos2) {
    int n = blockIdx.x * 256 + threadIdx.x;
    if (n >= NN) return;
    int running = rowptr[n];
    #pragma unroll
    for (int t = 0; t < NT; ++t) {
        fillpos2[n * NT + t] = running;
        running += cnt2[n * NT + t];
    }
}

// ---------------- XCD-local CSR fill, tile-bucketed (sorted col) ------------
__global__ void __launch_bounds__(256)
fill_csr3(const int* __restrict__ ebuf, const int* __restrict__ flag,
          int* __restrict__ fillpos2, int* __restrict__ col) {
    int rng = blockIdx.x & 7;
    int lo = rng * (NN / 8), hi = lo + (NN / 8);
    int is64 = flag[0];
    int stride = (gridDim.x >> 3) * 256;
    for (int e = (blockIdx.x >> 3) * 256 + threadIdx.x; e < NE; e += stride) {
        int d = edge_at(ebuf, is64, NE + e);
        if (d >= lo && d < hi) {
            int s = edge_at(ebuf, is64, e);
            int p = atomicAdd(&fillpos2[d * NT + (s >> TSH)], 1);
            col[p] = s;
        }
    }
}

// ---------------- x -> bf16 row-major [NN][128] ----------------
__global__ void conv_x(const float* __restrict__ x, ushort* __restrict__ xb) {
    int i = blockIdx.x * 256 + threadIdx.x;
    if (i >= NN * XBP) return;
    int n = i >> 7, c = i & 127;
    xb[i] = (c < INC) ? f2bf(x[(size_t)n * INC + c]) : (ushort)0;
}

// ---------------- weight decompose + transpose ----------------
__global__ void decomp_w1(const float* __restrict__ W, ushort* __restrict__ hi,
                          ushort* __restrict__ lo) {
    int i = blockIdx.x * 256 + threadIdx.x;   // 256*128
    int n = i >> 7, k = i & 127;
    float v = (k < INC) ? W[k * HID + n] : 0.f;
    ushort h = f2bf(v);
    hi[n * K1P + k] = h;
    lo[n * K1P + k] = f2bf(v - bf2f(h));
}

__global__ void decomp_w2(const float* __restrict__ W, ushort* __restrict__ hi,
                          ushort* __restrict__ lo) {
    int i = blockIdx.x * 256 + threadIdx.x;   // 256*256
    int n = i >> 8, k = i & 255;
    float v = W[k * HID + n];
    ushort h = f2bf(v);
    hi[n * HID + k] = h;
    lo[n * HID + k] = f2bf(v - bf2f(h));
}

// ---------------- layer-1 aggregate (round-5 structure + XCD node remap) ----
// one block per node; 16 groups x 16 lanes; lane c = 16B chunk (8 ch).
__global__ void __launch_bounds__(256)
agg1b(const ushort* __restrict__ xb, const float* __restrict__ x,
      const float* __restrict__ dinv, const int* __restrict__ rowptr,
      const int* __restrict__ col, ushort* __restrict__ ohi, ushort* __restrict__ olo) {
    __shared__ float red[16][16][8];
    int bid = blockIdx.x;
    int n = (bid & 7) * (NN / 8) + (bid >> 3);   // XCD-contiguous node ranges
    int tid = threadIdx.x;
    int g = tid >> 4, c = tid & 15;
    int beg = rowptr[n], end = rowptr[n + 1];
    {
        float a0=0.f,a1=0.f,a2=0.f,a3=0.f,a4=0.f,a5=0.f,a6=0.f,a7=0.f;
        const ushort* hc = xb + c * 8;
        int j = beg + g;
        for (; j + 16 < end; j += 32) {
            int s0 = col[j], s1 = col[j + 16];
            float w0 = dinv[s0], w1 = dinv[s1];
            uint4 u0 = *(const uint4*)(hc + (size_t)s0 * XBP);
            uint4 u1 = *(const uint4*)(hc + (size_t)s1 * XBP);
            a0 += w0 * bflo(u0.x) + w1 * bflo(u1.x);
            a1 += w0 * bfhi(u0.x) + w1 * bfhi(u1.x);
            a2 += w0 * bflo(u0.y) + w1 * bflo(u1.y);
            a3 += w0 * bfhi(u0.y) + w1 * bfhi(u1.y);
            a4 += w0 * bflo(u0.z) + w1 * bflo(u1.z);
            a5 += w0 * bfhi(u0.z) + w1 * bfhi(u1.z);
            a6 += w0 * bflo(u0.w) + w1 * bflo(u1.w);
            a7 += w0 * bfhi(u0.w) + w1 * bfhi(u1.w);
        }
        if (j < end) {
            int s0 = col[j];
            float w0 = dinv[s0];
            uint4 u0 = *(const uint4*)(hc + (size_t)s0 * XBP);
            a0 += w0 * bflo(u0.x); a1 += w0 * bfhi(u0.x);
            a2 += w0 * bflo(u0.y); a3 += w0 * bfhi(u0.y);
            a4 += w0 * bflo(u0.z); a5 += w0 * bfhi(u0.z);
            a6 += w0 * bflo(u0.w); a7 += w0 * bfhi(u0.w);
        }
        red[g][c][0]=a0; red[g][c][1]=a1; red[g][c][2]=a2; red[g][c][3]=a3;
        red[g][c][4]=a4; red[g][c][5]=a5; red[g][c][6]=a6; red[g][c][7]=a7;
    }
    __syncthreads();
    int t = tid;
    if (t < K1P) {
        float s = 0.f;
        #pragma unroll
        for (int gg = 0; gg < 16; ++gg) s += red[gg][t >> 3][t & 7];
        float self = (t < INC) ? x[(size_t)n * INC + t] : 0.f;
        float dn = dinv[n];
        float r = dn * (s + dn * self);
        ushort h = f2bf(r);
        ohi[(size_t)n * K1P + t] = h;
        olo[(size_t)n * K1P + t] = f2bf(r - bf2f(h));
    }
}

// ---------------- layer-2 aggregate (round-5 structure + remap + 4-deep) ----
// one block per node; 8 groups x 32 lanes; lane c = 16B chunk (8 ch).
__global__ void __launch_bounds__(256)
agg2b(const ushort* __restrict__ hb, const float* __restrict__ dinv,
      const int* __restrict__ rowptr, const int* __restrict__ col,
      ushort* __restrict__ ohi, ushort* __restrict__ olo) {
    __shared__ float red[8][32][8];
    int bid = blockIdx.x;
    int n = (bid & 7) * (NN / 8) + (bid >> 3);   // XCD-contiguous node ranges
    int tid = threadIdx.x;
    int g = tid >> 5, c = tid & 31;
    int beg = rowptr[n], end = rowptr[n + 1];
    {
        float a0=0.f,a1=0.f,a2=0.f,a3=0.f,a4=0.f,a5=0.f,a6=0.f,a7=0.f;
        const ushort* hc = hb + c * 8;
        int j = beg + g;
        // 4-deep unroll: 4 outstanding row-gathers per lane
        for (; j + 24 < end; j += 32) {
            int s0 = col[j], s1 = col[j + 8], s2 = col[j + 16], s3 = col[j + 24];
            float w0 = dinv[s0], w1 = dinv[s1], w2 = dinv[s2], w3 = dinv[s3];
            uint4 u0 = *(const uint4*)(hc + (size_t)s0 * HID);
            uint4 u1 = *(const uint4*)(hc + (size_t)s1 * HID);
            uint4 u2 = *(const uint4*)(hc + (size_t)s2 * HID);
            uint4 u3 = *(const uint4*)(hc + (size_t)s3 * HID);
            a0 += w0 * bflo(u0.x) + w1 * bflo(u1.x) + w2 * bflo(u2.x) + w3 * bflo(u3.x);
            a1 += w0 * bfhi(u0.x) + w1 * bfhi(u1.x) + w2 * bfhi(u2.x) + w3 * bfhi(u3.x);
            a2 += w0 * bflo(u0.y) + w1 * bflo(u1.y) + w2 * bflo(u2.y) + w3 * bflo(u3.y);
            a3 += w0 * bfhi(u0.y) + w1 * bfhi(u1.y) + w2 * bfhi(u2.y) + w3 * bfhi(u3.y);
            a4 += w0 * bflo(u0.z) + w1 * bflo(u1.z) + w2 * bflo(u2.z) + w3 * bflo(u3.z);
            a5 += w0 * bfhi(u0.z) + w1 * bfhi(u1.z) + w2 * bfhi(u2.z) + w3 * bfhi(u3.z);
            a6 += w0 * bflo(u0.w) + w1 * bflo(u1.w) + w2 * bflo(u2.w) + w3 * bflo(u3.w);
            a7 += w0 * bfhi(u0.w) + w1 * bfhi(u1.w) + w2 * bfhi(u2.w) + w3 * bfhi(u3.w);
        }
        for (; j < end; j += 8) {
            int s0 = col[j];
            float w0 = dinv[s0];
            uint4 u0 = *(const uint4*)(hc + (size_t)s0 * HID);
            a0 += w0 * bflo(u0.x); a1 += w0 * bfhi(u0.x);
            a2 += w0 * bflo(u0.y); a3 += w0 * bfhi(u0.y);
            a4 += w0 * bflo(u0.z); a5 += w0 * bfhi(u0.z);
            a6 += w0 * bflo(u0.w); a7 += w0 * bfhi(u0.w);
        }
        red[g][c][0]=a0; red[g][c][1]=a1; red[g][c][2]=a2; red[g][c][3]=a3;
        red[g][c][4]=a4; red[g][c][5]=a5; red[g][c][6]=a6; red[g][c][7]=a7;
    }
    __syncthreads();
    int t = tid;
    float s = 0.f;
    #pragma unroll
    for (int gg = 0; gg < 8; ++gg) s += red[gg][t >> 3][t & 7];
    float dn = dinv[n];
    float self = bf2f(hb[(size_t)n * HID + t]);
    float r = dn * (s + dn * self);
    ushort h = f2bf(r);
    ohi[(size_t)n * HID + t] = h;
    olo[(size_t)n * HID + t] = f2bf(r - bf2f(h));
}

// ---------------- MFMA GEMM, split-bf16 fp32 emulation -----------------------
// MODE 1: C = bf16( relu(A@Bt + bias) ) row-major   (layer 1 -> h1b)
// MODE 2: fused layer-3: v = relu(A@Bt + bias); atomicAdd hw3[row] += v @ W3
template <int MODE>
__global__ void __launch_bounds__(256)
gemm_mfma(const ushort* __restrict__ Ahi, const ushort* __restrict__ Alo,
          const ushort* __restrict__ Bhi, const ushort* __restrict__ Blo,
          const float* __restrict__ bias, ushort* __restrict__ Cb,
          const float* __restrict__ W3, float* __restrict__ hw3,
          int M, int K, int Nn) {
    constexpr int BM = 128, BN = 128, BK = 32, LDK = BK + 8;
    __shared__ ushort sAh[BM * LDK], sAl[BM * LDK];
    __shared__ ushort sBh[BN * LDK], sBl[BN * LDK];
    int tid = threadIdx.x;
    int w = tid >> 6, l = tid & 63;
    int wr = w >> 1, wc = w & 1;
    int bm = blockIdx.x * BM, bn = blockIdx.y * BN;
    int l15 = l & 15, kg = l >> 4;
    f32x4 zero = {0.f, 0.f, 0.f, 0.f};
    f32x4 acc[4][4];
    #pragma unroll
    for (int i = 0; i < 4; ++i)
        #pragma unroll
        for (int j = 0; j < 4; ++j) acc[i][j] = zero;

    for (int kb = 0; kb < K; kb += BK) {
        #pragma unroll
        for (int it = 0; it < 2; ++it) {
            int cc = tid + it * 256;
            int row = cc >> 2, kp = (cc & 3) * 8;
            int ar = bm + row;
            float4 z4 = make_float4(0.f, 0.f, 0.f, 0.f);
            float4 avh = z4, avl = z4;
            if (ar < M) {
                avh = *(const float4*)(Ahi + (size_t)ar * K + kb + kp);
                avl = *(const float4*)(Alo + (size_t)ar * K + kb + kp);
            }
            *(float4*)&sAh[row * LDK + kp] = avh;
            *(float4*)&sAl[row * LDK + kp] = avl;
            int br = bn + row;  // Nn == 256 always covers
            float4 bvh = *(const float4*)(Bhi + (size_t)br * K + kb + kp);
            float4 bvl = *(const float4*)(Blo + (size_t)br * K + kb + kp);
            *(float4*)&sBh[row * LDK + kp] = bvh;
            *(float4*)&sBl[row * LDK + kp] = bvl;
        }
        __syncthreads();
        s16x8 ah[4], al[4], bh[4], bl[4];
        #pragma unroll
        for (int i = 0; i < 4; ++i) {
            int arow = wr * 64 + i * 16 + l15;
            ah[i] = *(const s16x8*)&sAh[arow * LDK + kg * 8];
            al[i] = *(const s16x8*)&sAl[arow * LDK + kg * 8];
            int brow = wc * 64 + i * 16 + l15;
            bh[i] = *(const s16x8*)&sBh[brow * LDK + kg * 8];
            bl[i] = *(const s16x8*)&sBl[brow * LDK + kg * 8];
        }
        #pragma unroll
        for (int i = 0; i < 4; ++i)
            #pragma unroll
            for (int j = 0; j < 4; ++j) {
                acc[i][j] = __builtin_amdgcn_mfma_f32_16x16x32_bf16(ah[i], bh[j], acc[i][j], 0, 0, 0);
                acc[i][j] = __builtin_amdgcn_mfma_f32_16x16x32_bf16(ah[i], bl[j], acc[i][j], 0, 0, 0);
                acc[i][j] = __builtin_amdgcn_mfma_f32_16x16x32_bf16(al[i], bh[j], acc[i][j], 0, 0, 0);
            }
        __syncthreads();
    }
    // C/D layout: col = l&15, row = (l>>4)*4 + r
    if (MODE == 1) {
        #pragma unroll
        for (int j = 0; j < 4; ++j) {
            int cn = bn + wc * 64 + j * 16 + l15;
            float bv = bias[cn];
            #pragma unroll
            for (int i = 0; i < 4; ++i) {
                int rbase = bm + wr * 64 + i * 16 + kg * 4;
                #pragma unroll
                for (int r = 0; r < 4; ++r) {
                    int rm = rbase + r;
                    if (rm < M) {
                        float v = fmaxf(acc[i][j][r] + bv, 0.f);
                        Cb[(size_t)rm * Nn + cn] = f2bf(v);
                    }
                }
            }
        }
    } else {
        float p0[4][4], p1[4][4];
        #pragma unroll
        for (int i = 0; i < 4; ++i)
            #pragma unroll
            for (int r = 0; r < 4; ++r) { p0[i][r] = 0.f; p1[i][r] = 0.f; }
        #pragma unroll
        for (int j = 0; j < 4; ++j) {
            int cn = bn + wc * 64 + j * 16 + l15;
            float bv = bias[cn];
            float w30 = W3[cn * 2 + 0], w31 = W3[cn * 2 + 1];
            #pragma unroll
            for (int i = 0; i < 4; ++i)
                #pragma unroll
                for (int r = 0; r < 4; ++r) {
                    float v = fmaxf(acc[i][j][r] + bv, 0.f);
                    p0[i][r] += v * w30;
                    p1[i][r] += v * w31;
                }
        }
        #pragma unroll
        for (int i = 0; i < 4; ++i)
            #pragma unroll
            for (int r = 0; r < 4; ++r) {
                float q0 = p0[i][r], q1 = p1[i][r];
                #pragma unroll
                for (int off = 1; off < 16; off <<= 1) {
                    q0 += __shfl_xor(q0, off);
                    q1 += __shfl_xor(q1, off);
                }
                if (l15 == 0) {
                    int rm = bm + wr * 64 + i * 16 + kg * 4 + r;
                    if (rm < M) {
                        atomicAdd(&hw3[rm * 2 + 0], q0);
                        atomicAdd(&hw3[rm * 2 + 1], q1);
                    }
                }
            }
    }
}

// ---------------- layer-3 aggregation (2 channels) ---------------------------
__global__ void agg3(const float* __restrict__ hw3, const float* __restrict__ dinv,
                     const int* __restrict__ rowptr, const int* __restrict__ col,
                     const float* __restrict__ b3, float* __restrict__ out) {
    int n = blockIdx.x * blockDim.x + threadIdx.x;
    if (n >= NN) return;
    float a0 = 0.f, a1 = 0.f;
    int beg = rowptr[n], end = rowptr[n + 1];
    for (int j = beg; j < end; ++j) {
        int s = col[j];
        float w = dinv[s];
        float2 v = ((const float2*)hw3)[s];
        a0 += w * v.x;
        a1 += w * v.y;
    }
    float dn = dinv[n];
    float2 sv = ((const float2*)hw3)[n];
    out[n * 2 + 0] = dn * (a0 + dn * sv.x) + b3[0];
    out[n * 2 + 1] = dn * (a1 + dn * sv.y) + b3[1];
}

extern "C" void kernel_launch(void* const* d_in, const int* in_sizes, int n_in,
                              void* d_out, int out_size, void* d_ws, size_t ws_size,
                              hipStream_t stream) {
    const float* x   = (const float*)d_in[0];
    const int*   ebf = (const int*)d_in[1];
    const float* W1  = (const float*)d_in[2];
    const float* b1  = (const float*)d_in[3];
    const float* W2  = (const float*)d_in[4];
    const float* b2  = (const float*)d_in[5];
    const float* W3  = (const float*)d_in[6];
    const float* b3  = (const float*)d_in[7];
    float* out = (float*)d_out;

    char* ws = (char*)d_ws;
    size_t off = 0;
    auto carve = [&](size_t bytes) -> char* {
        char* p = ws + off;
        off += (bytes + 255) & ~(size_t)255;
        return p;
    };
    int*    flag    = (int*)   carve(256);
    int*    cnt     = (int*)   carve((size_t)NN * 4);
    int*    cnt2    = (int*)   carve((size_t)NN * NT * 4);
    float*  dinv    = (float*) carve((size_t)NN * 4);
    int*    rowptr  = (int*)   carve((size_t)(NN + 1) * 4);
    int*    fillpos2= (int*)   carve((size_t)NN * NT * 4);
    int*    bsum    = (int*)   carve(256 * 4);
    int*    col     = (int*)   carve((size_t)NE * 4);
    ushort* xb      = (ushort*)carve((size_t)NN * XBP * 2);
    ushort* W1thi   = (ushort*)carve((size_t)HID * K1P * 2);
    ushort* W1tlo   = (ushort*)carve((size_t)HID * K1P * 2);
    ushort* W2thi   = (ushort*)carve((size_t)HID * HID * 2);
    ushort* W2tlo   = (ushort*)carve((size_t)HID * HID * 2);
    ushort* a1hi    = (ushort*)carve((size_t)NN * K1P * 2);
    ushort* a1lo    = (ushort*)carve((size_t)NN * K1P * 2);
    ushort* h1b     = (ushort*)carve((size_t)NN * HID * 2);
    ushort* a2hi    = (ushort*)carve((size_t)NN * HID * 2);
    ushort* a2lo    = (ushort*)carve((size_t)NN * HID * 2);
    float*  hw3     = (float*) carve((size_t)NN * OUTC * 4);
    (void)ws_size; (void)n_in; (void)in_sizes; (void)out_size;

    const int SCAN_G = (NN + 255) / 256;

    hipMemsetAsync(cnt2, 0, (size_t)NN * NT * 4, stream);
    hipMemsetAsync(hw3, 0, (size_t)NN * OUTC * 4, stream);
    detect_fmt<<<1, 64, 0, stream>>>(ebf, flag);
    deg_hist3<<<2048, 256, 0, stream>>>(ebf, flag, cnt2);
    sum_cnt<<<SCAN_G, 256, 0, stream>>>(cnt2, cnt, dinv);
    scan1<<<SCAN_G, 256, 0, stream>>>(cnt, rowptr, bsum);
    scan2<<<1, 256, 0, stream>>>(bsum, SCAN_G);
    scan3<<<SCAN_G, 256, 0, stream>>>(rowptr, bsum);
    mk_rowptr2<<<SCAN_G, 256, 0, stream>>>(rowptr, cnt2, fillpos2);
    fill_csr3<<<2048, 256, 0, stream>>>(ebf, flag, fillpos2, col);
    conv_x<<<((size_t)NN * XBP + 255) / 256, 256, 0, stream>>>(x, xb);
    decomp_w1<<<(HID * K1P) / 256, 256, 0, stream>>>(W1, W1thi, W1tlo);
    decomp_w2<<<(HID * HID) / 256, 256, 0, stream>>>(W2, W2thi, W2tlo);

    // layer 1: bf16 gather-aggregate x, MFMA 128->256 + relu -> bf16 h1
    agg1b<<<NN, 256, 0, stream>>>(xb, x, dinv, rowptr, col, a1hi, a1lo);
    {
        dim3 g((NN + 127) / 128, HID / 128);
        gemm_mfma<1><<<g, 256, 0, stream>>>(a1hi, a1lo, W1thi, W1tlo, b1, h1b,
                                            nullptr, nullptr, NN, K1P, HID);
    }
    // layer 2: bf16 gather-aggregate h1, MFMA 256->256 + relu, fused @W3 -> hw3
    agg2b<<<NN, 256, 0, stream>>>(h1b, dinv, rowptr, col, a2hi, a2lo);
    {
        dim3 g((NN + 127) / 128, HID / 128);
        gemm_mfma<2><<<g, 256, 0, stream>>>(a2hi, a2lo, W2thi, W2tlo, b2, nullptr,
                                            W3, hw3, NN, HID, HID);
    }
    // layer 3: 2-channel aggregation + bias
    agg3<<<SCAN_G, 256, 0, stream>>>(hw3, dinv, rowptr, col, b3, out);
}

// Round 10
// 515.617 us; speedup vs baseline: 1.3410x; 1.0141x over previous
//
#include <hip/hip_runtime.h>
#include <hip/hip_bf16.h>
#include <stdint.h>

#define NN 50000
#define NE 1600000
#define INC 116
#define XBP 128     // bf16-padded x row stride (256B rows)
#define K1P 128
#define HID 256
#define OUTC 2
#define NT 13       // source tiles of 4096 nodes
#define TSH 12

typedef float f32x4 __attribute__((ext_vector_type(4)));
typedef short s16x8 __attribute__((ext_vector_type(8)));

__device__ __forceinline__ ushort f2bf(float v) {
    uint32_t u = __float_as_uint(v);
    return (ushort)((u + 0x7FFFu + ((u >> 16) & 1u)) >> 16);
}
__device__ __forceinline__ float bf2f(ushort b) {
    return __uint_as_float(((uint32_t)b) << 16);
}
__device__ __forceinline__ float bflo(uint32_t u) { return __uint_as_float(u << 16); }
__device__ __forceinline__ float bfhi(uint32_t u) { return __uint_as_float(u & 0xFFFF0000u); }

// ---------------- edge-index format hedge (int32 vs int64) ----------------
__global__ void detect_fmt(const int* __restrict__ ebuf, int* __restrict__ flag) {
    int v = ebuf[2 * threadIdx.x + 1];
    unsigned long long b = __ballot(v != 0);
    if (threadIdx.x == 0) flag[0] = (b == 0ULL) ? 1 : 0;
}

__device__ __forceinline__ int edge_at(const int* __restrict__ ebuf, int is64, int idx) {
    return is64 ? ebuf[2 * idx] : ebuf[idx];
}

// ---------------- (dst, src-tile) histogram, XCD-local dst ranges ----------
__global__ void __launch_bounds__(256)
deg_hist3(const int* __restrict__ ebuf, const int* __restrict__ flag,
          int* __restrict__ cnt2) {
    int rng = blockIdx.x & 7;
    int lo = rng * (NN / 8), hi = lo + (NN / 8);
    int is64 = flag[0];
    int stride = (gridDim.x >> 3) * 256;
    for (int e = (blockIdx.x >> 3) * 256 + threadIdx.x; e < NE; e += stride) {
        int d = edge_at(ebuf, is64, NE + e);
        if (d >= lo && d < hi) {
            int s = edge_at(ebuf, is64, e);
            atomicAdd(&cnt2[d * NT + (s >> TSH)], 1);
        }
    }
}

// ---------------- fused: per-node total + dinv + block scan ----------------
__global__ void scan1b(const int* __restrict__ cnt2, float* __restrict__ dinv,
                       int* __restrict__ rowptr, int* __restrict__ bsum) {
    __shared__ int s[256];
    int tid = threadIdx.x;
    int i = blockIdx.x * 256 + tid;
    int v = 0;
    if (i < NN) {
        #pragma unroll
        for (int t = 0; t < NT; ++t) v += cnt2[i * NT + t];
        dinv[i] = rsqrtf((float)v + 1.0f);
    }
    s[tid] = v;
    __syncthreads();
    for (int off = 1; off < 256; off <<= 1) {
        int t = (tid >= off) ? s[tid - off] : 0;
        __syncthreads();
        s[tid] += t;
        __syncthreads();
    }
    if (i < NN) rowptr[i] = s[tid] - v;      // block-local exclusive
    if (tid == 255) bsum[blockIdx.x] = s[255];
}

__global__ void scan2(int* __restrict__ bsum, int nblocks) {
    __shared__ int s[256];
    int tid = threadIdx.x;
    int v = (tid < nblocks) ? bsum[tid] : 0;
    s[tid] = v;
    __syncthreads();
    for (int off = 1; off < 256; off <<= 1) {
        int t = (tid >= off) ? s[tid - off] : 0;
        __syncthreads();
        s[tid] += t;
        __syncthreads();
    }
    if (tid < nblocks) bsum[tid] = s[tid] - v;
}

// ---------------- fused: final rowptr + per-tile fill positions ------------
__global__ void scan3m(int* __restrict__ rowptr, const int* __restrict__ bsum,
                       const int* __restrict__ cnt2, int* __restrict__ fillpos2) {
    int i = blockIdx.x * 256 + threadIdx.x;
    if (i < NN) {
        int r = rowptr[i] + bsum[blockIdx.x];
        rowptr[i] = r;
        int running = r;
        #pragma unroll
        for (int t = 0; t < NT; ++t) {
            fillpos2[i * NT + t] = running;
            running += cnt2[i * NT + t];
        }
        if (i == NN - 1) rowptr[NN] = NE;
    }
}

// ---------------- XCD-local CSR fill, tile-bucketed (sorted col) ------------
__global__ void __launch_bounds__(256)
fill_csr3(const int* __restrict__ ebuf, const int* __restrict__ flag,
          int* __restrict__ fillpos2, int* __restrict__ col) {
    int rng = blockIdx.x & 7;
    int lo = rng * (NN / 8), hi = lo + (NN / 8);
    int is64 = flag[0];
    int stride = (gridDim.x >> 3) * 256;
    for (int e = (blockIdx.x >> 3) * 256 + threadIdx.x; e < NE; e += stride) {
        int d = edge_at(ebuf, is64, NE + e);
        if (d >= lo && d < hi) {
            int s = edge_at(ebuf, is64, e);
            int p = atomicAdd(&fillpos2[d * NT + (s >> TSH)], 1);
            col[p] = s;
        }
    }
}

// ---------------- fused prep: conv_x + decomp_w1 + decomp_w2 ----------------
// blocks [0,25000): xb; [25000,25128): W1t; [25128,25384): W2t
__global__ void prep(const float* __restrict__ x, ushort* __restrict__ xb,
                     const float* __restrict__ W1, ushort* __restrict__ w1hi,
                     ushort* __restrict__ w1lo,
                     const float* __restrict__ W2, ushort* __restrict__ w2hi,
                     ushort* __restrict__ w2lo) {
    int b = blockIdx.x;
    int tid = threadIdx.x;
    if (b < 25000) {
        int i = b * 256 + tid;                  // exactly NN*XBP
        int n = i >> 7, c = i & 127;
        xb[i] = (c < INC) ? f2bf(x[(size_t)n * INC + c]) : (ushort)0;
    } else if (b < 25128) {
        int i = (b - 25000) * 256 + tid;        // 256*128
        int n = i >> 7, k = i & 127;
        float v = (k < INC) ? W1[k * HID + n] : 0.f;
        ushort h = f2bf(v);
        w1hi[n * K1P + k] = h;
        w1lo[n * K1P + k] = f2bf(v - bf2f(h));
    } else {
        int i = (b - 25128) * 256 + tid;        // 256*256
        int n = i >> 8, k = i & 255;
        float v = W2[k * HID + n];
        ushort h = f2bf(v);
        w2hi[n * HID + k] = h;
        w2lo[n * HID + k] = f2bf(v - bf2f(h));
    }
}

// ---------------- layer-1 aggregate (unchanged from round 8) ----------------
__global__ void __launch_bounds__(256)
agg1b(const ushort* __restrict__ xb, const float* __restrict__ x,
      const float* __restrict__ dinv, const int* __restrict__ rowptr,
      const int* __restrict__ col, ushort* __restrict__ ohi, ushort* __restrict__ olo) {
    __shared__ float red[16][16][8];
    int bid = blockIdx.x;
    int n = (bid & 7) * (NN / 8) + (bid >> 3);
    int tid = threadIdx.x;
    int g = tid >> 4, c = tid & 15;
    int beg = rowptr[n], end = rowptr[n + 1];
    {
        float a0=0.f,a1=0.f,a2=0.f,a3=0.f,a4=0.f,a5=0.f,a6=0.f,a7=0.f;
        const ushort* hc = xb + c * 8;
        int j = beg + g;
        for (; j + 16 < end; j += 32) {
            int s0 = col[j], s1 = col[j + 16];
            float w0 = dinv[s0], w1 = dinv[s1];
            uint4 u0 = *(const uint4*)(hc + (size_t)s0 * XBP);
            uint4 u1 = *(const uint4*)(hc + (size_t)s1 * XBP);
            a0 += w0 * bflo(u0.x) + w1 * bflo(u1.x);
            a1 += w0 * bfhi(u0.x) + w1 * bfhi(u1.x);
            a2 += w0 * bflo(u0.y) + w1 * bflo(u1.y);
            a3 += w0 * bfhi(u0.y) + w1 * bfhi(u1.y);
            a4 += w0 * bflo(u0.z) + w1 * bflo(u1.z);
            a5 += w0 * bfhi(u0.z) + w1 * bfhi(u1.z);
            a6 += w0 * bflo(u0.w) + w1 * bflo(u1.w);
            a7 += w0 * bfhi(u0.w) + w1 * bfhi(u1.w);
        }
        if (j < end) {
            int s0 = col[j];
            float w0 = dinv[s0];
            uint4 u0 = *(const uint4*)(hc + (size_t)s0 * XBP);
            a0 += w0 * bflo(u0.x); a1 += w0 * bfhi(u0.x);
            a2 += w0 * bflo(u0.y); a3 += w0 * bfhi(u0.y);
            a4 += w0 * bflo(u0.z); a5 += w0 * bfhi(u0.z);
            a6 += w0 * bflo(u0.w); a7 += w0 * bfhi(u0.w);
        }
        red[g][c][0]=a0; red[g][c][1]=a1; red[g][c][2]=a2; red[g][c][3]=a3;
        red[g][c][4]=a4; red[g][c][5]=a5; red[g][c][6]=a6; red[g][c][7]=a7;
    }
    __syncthreads();
    int t = tid;
    if (t < K1P) {
        float s = 0.f;
        #pragma unroll
        for (int gg = 0; gg < 16; ++gg) s += red[gg][t >> 3][t & 7];
        float self = (t < INC) ? x[(size_t)n * INC + t] : 0.f;
        float dn = dinv[n];
        float r = dn * (s + dn * self);
        ushort h = f2bf(r);
        ohi[(size_t)n * K1P + t] = h;
        olo[(size_t)n * K1P + t] = f2bf(r - bf2f(h));
    }
}

// ---------------- layer-2 aggregate (unchanged from round 8) ----------------
__global__ void __launch_bounds__(256)
agg2b(const ushort* __restrict__ hb, const float* __restrict__ dinv,
      const int* __restrict__ rowptr, const int* __restrict__ col,
      ushort* __restrict__ ohi, ushort* __restrict__ olo) {
    __shared__ float red[8][32][8];
    int bid = blockIdx.x;
    int n = (bid & 7) * (NN / 8) + (bid >> 3);
    int tid = threadIdx.x;
    int g = tid >> 5, c = tid & 31;
    int beg = rowptr[n], end = rowptr[n + 1];
    {
        float a0=0.f,a1=0.f,a2=0.f,a3=0.f,a4=0.f,a5=0.f,a6=0.f,a7=0.f;
        const ushort* hc = hb + c * 8;
        int j = beg + g;
        for (; j + 24 < end; j += 32) {
            int s0 = col[j], s1 = col[j + 8], s2 = col[j + 16], s3 = col[j + 24];
            float w0 = dinv[s0], w1 = dinv[s1], w2 = dinv[s2], w3 = dinv[s3];
            uint4 u0 = *(const uint4*)(hc + (size_t)s0 * HID);
            uint4 u1 = *(const uint4*)(hc + (size_t)s1 * HID);
            uint4 u2 = *(const uint4*)(hc + (size_t)s2 * HID);
            uint4 u3 = *(const uint4*)(hc + (size_t)s3 * HID);
            a0 += w0 * bflo(u0.x) + w1 * bflo(u1.x) + w2 * bflo(u2.x) + w3 * bflo(u3.x);
            a1 += w0 * bfhi(u0.x) + w1 * bfhi(u1.x) + w2 * bfhi(u2.x) + w3 * bfhi(u3.x);
            a2 += w0 * bflo(u0.y) + w1 * bflo(u1.y) + w2 * bflo(u2.y) + w3 * bflo(u3.y);
            a3 += w0 * bfhi(u0.y) + w1 * bfhi(u1.y) + w2 * bfhi(u2.y) + w3 * bfhi(u3.y);
            a4 += w0 * bflo(u0.z) + w1 * bflo(u1.z) + w2 * bflo(u2.z) + w3 * bflo(u3.z);
            a5 += w0 * bfhi(u0.z) + w1 * bfhi(u1.z) + w2 * bfhi(u2.z) + w3 * bfhi(u3.z);
            a6 += w0 * bflo(u0.w) + w1 * bflo(u1.w) + w2 * bflo(u2.w) + w3 * bflo(u3.w);
            a7 += w0 * bfhi(u0.w) + w1 * bfhi(u1.w) + w2 * bfhi(u2.w) + w3 * bfhi(u3.w);
        }
        for (; j < end; j += 8) {
            int s0 = col[j];
            float w0 = dinv[s0];
            uint4 u0 = *(const uint4*)(hc + (size_t)s0 * HID);
            a0 += w0 * bflo(u0.x); a1 += w0 * bfhi(u0.x);
            a2 += w0 * bflo(u0.y); a3 += w0 * bfhi(u0.y);
            a4 += w0 * bflo(u0.z); a5 += w0 * bfhi(u0.z);
            a6 += w0 * bflo(u0.w); a7 += w0 * bfhi(u0.w);
        }
        red[g][c][0]=a0; red[g][c][1]=a1; red[g][c][2]=a2; red[g][c][3]=a3;
        red[g][c][4]=a4; red[g][c][5]=a5; red[g][c][6]=a6; red[g][c][7]=a7;
    }
    __syncthreads();
    int t = tid;
    float s = 0.f;
    #pragma unroll
    for (int gg = 0; gg < 8; ++gg) s += red[gg][t >> 3][t & 7];
    float dn = dinv[n];
    float self = bf2f(hb[(size_t)n * HID + t]);
    float r = dn * (s + dn * self);
    ushort h = f2bf(r);
    ohi[(size_t)n * HID + t] = h;
    olo[(size_t)n * HID + t] = f2bf(r - bf2f(h));
}

// ---------------- MFMA GEMM, split-bf16 fp32 emulation (unchanged) ----------
template <int MODE>
__global__ void __launch_bounds__(256)
gemm_mfma(const ushort* __restrict__ Ahi, const ushort* __restrict__ Alo,
          const ushort* __restrict__ Bhi, const ushort* __restrict__ Blo,
          const float* __restrict__ bias, ushort* __restrict__ Cb,
          const float* __restrict__ W3, float* __restrict__ hw3,
          int M, int K, int Nn) {
    constexpr int BM = 128, BN = 128, BK = 32, LDK = BK + 8;
    __shared__ ushort sAh[BM * LDK], sAl[BM * LDK];
    __shared__ ushort sBh[BN * LDK], sBl[BN * LDK];
    int tid = threadIdx.x;
    int w = tid >> 6, l = tid & 63;
    int wr = w >> 1, wc = w & 1;
    int bm = blockIdx.x * BM, bn = blockIdx.y * BN;
    int l15 = l & 15, kg = l >> 4;
    f32x4 zero = {0.f, 0.f, 0.f, 0.f};
    f32x4 acc[4][4];
    #pragma unroll
    for (int i = 0; i < 4; ++i)
        #pragma unroll
        for (int j = 0; j < 4; ++j) acc[i][j] = zero;

    for (int kb = 0; kb < K; kb += BK) {
        #pragma unroll
        for (int it = 0; it < 2; ++it) {
            int cc = tid + it * 256;
            int row = cc >> 2, kp = (cc & 3) * 8;
            int ar = bm + row;
            float4 z4 = make_float4(0.f, 0.f, 0.f, 0.f);
            float4 avh = z4, avl = z4;
            if (ar < M) {
                avh = *(const float4*)(Ahi + (size_t)ar * K + kb + kp);
                avl = *(const float4*)(Alo + (size_t)ar * K + kb + kp);
            }
            *(float4*)&sAh[row * LDK + kp] = avh;
            *(float4*)&sAl[row * LDK + kp] = avl;
            int br = bn + row;
            float4 bvh = *(const float4*)(Bhi + (size_t)br * K + kb + kp);
            float4 bvl = *(const float4*)(Blo + (size_t)br * K + kb + kp);
            *(float4*)&sBh[row * LDK + kp] = bvh;
            *(float4*)&sBl[row * LDK + kp] = bvl;
        }
        __syncthreads();
        s16x8 ah[4], al[4], bh[4], bl[4];
        #pragma unroll
        for (int i = 0; i < 4; ++i) {
            int arow = wr * 64 + i * 16 + l15;
            ah[i] = *(const s16x8*)&sAh[arow * LDK + kg * 8];
            al[i] = *(const s16x8*)&sAl[arow * LDK + kg * 8];
            int brow = wc * 64 + i * 16 + l15;
            bh[i] = *(const s16x8*)&sBh[brow * LDK + kg * 8];
            bl[i] = *(const s16x8*)&sBl[brow * LDK + kg * 8];
        }
        #pragma unroll
        for (int i = 0; i < 4; ++i)
            #pragma unroll
            for (int j = 0; j < 4; ++j) {
                acc[i][j] = __builtin_amdgcn_mfma_f32_16x16x32_bf16(ah[i], bh[j], acc[i][j], 0, 0, 0);
                acc[i][j] = __builtin_amdgcn_mfma_f32_16x16x32_bf16(ah[i], bl[j], acc[i][j], 0, 0, 0);
                acc[i][j] = __builtin_amdgcn_mfma_f32_16x16x32_bf16(al[i], bh[j], acc[i][j], 0, 0, 0);
            }
        __syncthreads();
    }
    if (MODE == 1) {
        #pragma unroll
        for (int j = 0; j < 4; ++j) {
            int cn = bn + wc * 64 + j * 16 + l15;
            float bv = bias[cn];
            #pragma unroll
            for (int i = 0; i < 4; ++i) {
                int rbase = bm + wr * 64 + i * 16 + kg * 4;
                #pragma unroll
                for (int r = 0; r < 4; ++r) {
                    int rm = rbase + r;
                    if (rm < M) {
                        float v = fmaxf(acc[i][j][r] + bv, 0.f);
                        Cb[(size_t)rm * Nn + cn] = f2bf(v);
                    }
                }
            }
        }
    } else {
        float p0[4][4], p1[4][4];
        #pragma unroll
        for (int i = 0; i < 4; ++i)
            #pragma unroll
            for (int r = 0; r < 4; ++r) { p0[i][r] = 0.f; p1[i][r] = 0.f; }
        #pragma unroll
        for (int j = 0; j < 4; ++j) {
            int cn = bn + wc * 64 + j * 16 + l15;
            float bv = bias[cn];
            float w30 = W3[cn * 2 + 0], w31 = W3[cn * 2 + 1];
            #pragma unroll
            for (int i = 0; i < 4; ++i)
                #pragma unroll
                for (int r = 0; r < 4; ++r) {
                    float v = fmaxf(acc[i][j][r] + bv, 0.f);
                    p0[i][r] += v * w30;
                    p1[i][r] += v * w31;
                }
        }
        #pragma unroll
        for (int i = 0; i < 4; ++i)
            #pragma unroll
            for (int r = 0; r < 4; ++r) {
                float q0 = p0[i][r], q1 = p1[i][r];
                #pragma unroll
                for (int off = 1; off < 16; off <<= 1) {
                    q0 += __shfl_xor(q0, off);
                    q1 += __shfl_xor(q1, off);
                }
                if (l15 == 0) {
                    int rm = bm + wr * 64 + i * 16 + kg * 4 + r;
                    if (rm < M) {
                        atomicAdd(&hw3[rm * 2 + 0], q0);
                        atomicAdd(&hw3[rm * 2 + 1], q1);
                    }
                }
            }
    }
}

// ---------------- layer-3 aggregation (2 channels) ---------------------------
__global__ void agg3(const float* __restrict__ hw3, const float* __restrict__ dinv,
                     const int* __restrict__ rowptr, const int* __restrict__ col,
                     const float* __restrict__ b3, float* __restrict__ out) {
    int n = blockIdx.x * blockDim.x + threadIdx.x;
    if (n >= NN) return;
    float a0 = 0.f, a1 = 0.f;
    int beg = rowptr[n], end = rowptr[n + 1];
    for (int j = beg; j < end; ++j) {
        int s = col[j];
        float w = dinv[s];
        float2 v = ((const float2*)hw3)[s];
        a0 += w * v.x;
        a1 += w * v.y;
    }
    float dn = dinv[n];
    float2 sv = ((const float2*)hw3)[n];
    out[n * 2 + 0] = dn * (a0 + dn * sv.x) + b3[0];
    out[n * 2 + 1] = dn * (a1 + dn * sv.y) + b3[1];
}

extern "C" void kernel_launch(void* const* d_in, const int* in_sizes, int n_in,
                              void* d_out, int out_size, void* d_ws, size_t ws_size,
                              hipStream_t stream) {
    const float* x   = (const float*)d_in[0];
    const int*   ebf = (const int*)d_in[1];
    const float* W1  = (const float*)d_in[2];
    const float* b1  = (const float*)d_in[3];
    const float* W2  = (const float*)d_in[4];
    const float* b2  = (const float*)d_in[5];
    const float* W3  = (const float*)d_in[6];
    const float* b3  = (const float*)d_in[7];
    float* out = (float*)d_out;

    char* ws = (char*)d_ws;
    size_t off = 0;
    auto carve = [&](size_t bytes) -> char* {
        char* p = ws + off;
        off += (bytes + 255) & ~(size_t)255;
        return p;
    };
    int*    flag    = (int*)   carve(256);
    int*    cnt2    = (int*)   carve((size_t)NN * NT * 4);
    float*  dinv    = (float*) carve((size_t)NN * 4);
    int*    rowptr  = (int*)   carve((size_t)(NN + 1) * 4);
    int*    fillpos2= (int*)   carve((size_t)NN * NT * 4);
    int*    bsum    = (int*)   carve(256 * 4);
    int*    col     = (int*)   carve((size_t)NE * 4);
    ushort* xb      = (ushort*)carve((size_t)NN * XBP * 2);
    ushort* W1thi   = (ushort*)carve((size_t)HID * K1P * 2);
    ushort* W1tlo   = (ushort*)carve((size_t)HID * K1P * 2);
    ushort* W2thi   = (ushort*)carve((size_t)HID * HID * 2);
    ushort* W2tlo   = (ushort*)carve((size_t)HID * HID * 2);
    ushort* a1hi    = (ushort*)carve((size_t)NN * K1P * 2);
    ushort* a1lo    = (ushort*)carve((size_t)NN * K1P * 2);
    ushort* h1b     = (ushort*)carve((size_t)NN * HID * 2);
    ushort* a2hi    = (ushort*)carve((size_t)NN * HID * 2);
    ushort* a2lo    = (ushort*)carve((size_t)NN * HID * 2);
    float*  hw3     = (float*) carve((size_t)NN * OUTC * 4);
    (void)ws_size; (void)n_in; (void)in_sizes; (void)out_size;

    const int SCAN_G = (NN + 255) / 256;   // 196

    hipMemsetAsync(cnt2, 0, (size_t)NN * NT * 4, stream);
    hipMemsetAsync(hw3, 0, (size_t)NN * OUTC * 4, stream);
    detect_fmt<<<1, 64, 0, stream>>>(ebf, flag);
    deg_hist3<<<2048, 256, 0, stream>>>(ebf, flag, cnt2);
    scan1b<<<SCAN_G, 256, 0, stream>>>(cnt2, dinv, rowptr, bsum);
    scan2<<<1, 256, 0, stream>>>(bsum, SCAN_G);
    scan3m<<<SCAN_G, 256, 0, stream>>>(rowptr, bsum, cnt2, fillpos2);
    fill_csr3<<<2048, 256, 0, stream>>>(ebf, flag, fillpos2, col);
    prep<<<25384, 256, 0, stream>>>(x, xb, W1, W1thi, W1tlo, W2, W2thi, W2tlo);

    // layer 1: bf16 gather-aggregate x, MFMA 128->256 + relu -> bf16 h1
    agg1b<<<NN, 256, 0, stream>>>(xb, x, dinv, rowptr, col, a1hi, a1lo);
    {
        dim3 g((NN + 127) / 128, HID / 128);
        gemm_mfma<1><<<g, 256, 0, stream>>>(a1hi, a1lo, W1thi, W1tlo, b1, h1b,
                                            nullptr, nullptr, NN, K1P, HID);
    }
    // layer 2: bf16 gather-aggregate h1, MFMA 256->256 + relu, fused @W3 -> hw3
    agg2b<<<NN, 256, 0, stream>>>(h1b, dinv, rowptr, col, a2hi, a2lo);
    {
        dim3 g((NN + 127) / 128, HID / 128);
        gemm_mfma<2><<<g, 256, 0, stream>>>(a2hi, a2lo, W2thi, W2tlo, b2, nullptr,
                                            W3, hw3, NN, HID, HID);
    }
    // layer 3: 2-channel aggregation + bias
    agg3<<<SCAN_G, 256, 0, stream>>>(hw3, dinv, rowptr, col, b3, out);
}